// Round 3
// baseline (1659.014 us; speedup 1.0000x reference)
//
#include <hip/hip_runtime.h>
#include <hip/hip_bf16.h>

typedef _Float16 h16;
typedef _Float16 h16x8 __attribute__((ext_vector_type(8)));
typedef float    f32x4 __attribute__((ext_vector_type(4)));

#define MFMA(a,b,c) __builtin_amdgcn_mfma_f32_16x16x32_f16((a),(b),(c),0,0,0)

// H=2 B=64 LT=384 LI=128 L=512 D=768 K=V=384 DK=DV=768 LQ=24

__global__ __launch_bounds__(256) void k_diag(float* out, int n, float val) {
  int i = blockIdx.x * 256 + threadIdx.x;
  if (i < n) out[i] = val;
}

// ---------------- LayerNorm -> fp16 xn[b*512+l][768]  + per-row stats
__global__ __launch_bounds__(256) void k_ln(
    const float* __restrict__ text, const float* __restrict__ images,
    const float* __restrict__ g, const float* __restrict__ be,
    h16* __restrict__ xn, float* __restrict__ muv, float* __restrict__ rsd)
{
  int row = blockIdx.x;
  int b = row >> 9, l = row & 511;
  const float* src = (l < 384) ? (text + ((size_t)b*384 + l)*768)
                               : (images + ((size_t)b*128 + (l-384))*768);
  int t = threadIdx.x;
  float x0 = src[t], x1 = src[t+256], x2 = src[t+512];
  __shared__ float red[8];
  float s = x0 + x1 + x2;
  #pragma unroll
  for (int m = 32; m; m >>= 1) s += __shfl_xor(s, m);
  int wid = t >> 6;
  if ((t & 63) == 0) red[wid] = s;
  __syncthreads();
  float mu = (red[0]+red[1]+red[2]+red[3]) * (1.0f/768.0f);
  float d0 = x0-mu, d1 = x1-mu, d2 = x2-mu;
  float v = d0*d0 + d1*d1 + d2*d2;
  #pragma unroll
  for (int m = 32; m; m >>= 1) v += __shfl_xor(v, m);
  if ((t & 63) == 0) red[4+wid] = v;
  __syncthreads();
  float var = (red[4]+red[5]+red[6]+red[7]) * (1.0f/768.0f);
  float rstd = rsqrtf(var + 1e-5f);
  if (t == 0) { muv[row] = mu; rsd[row] = rstd; }
  h16* dst = xn + (size_t)row * 768;
  dst[t]     = (h16)(d0*rstd*g[t]     + be[t]);
  dst[t+256] = (h16)(d1*rstd*g[t+256] + be[t+256]);
  dst[t+512] = (h16)(d2*rstd*g[t+512] + be[t+512]);
}

// ---------------- weight prep: src (nmat,768,cols) f32 -> dst (nmat,cols,768) fp16
__global__ __launch_bounds__(256) void k_wprep(
    const float* __restrict__ src, h16* __restrict__ dst, int cols)
{
  __shared__ float tile[32][33];
  int m = blockIdx.z;
  int d0 = blockIdx.y * 32;
  int c0 = blockIdx.x * 32;
  const float* s = src + (size_t)m * 768 * cols;
  h16* dd = dst + (size_t)m * cols * 768;
  int tx = threadIdx.x & 31, ty = threadIdx.x >> 5;
  #pragma unroll
  for (int i = 0; i < 32; i += 8)
    tile[ty+i][tx] = s[(size_t)(d0+ty+i)*cols + c0 + tx];
  __syncthreads();
  #pragma unroll
  for (int i = 0; i < 32; i += 8)
    dd[(size_t)(c0+ty+i)*768 + d0 + tx] = (h16)tile[tx][ty+i];
}

// ---------------- GEMM: C[32768 x 768] = A[32768 x 768] x BT^T (+bias, pad-zero)
// AMODE 0: A = fp16 [gr][768]
// AMODE 1: A = LN(text/images) on the fly (f32 src + stats)
// AMODE 2: A = album stored in Q-layout: (h*64+b, l, c) head-split at d=384
// omode 0: out[((h*64+b)*512+l)*384+kk]   omode 1: out[gr*768+n]
#define LDSK 72
template<int AMODE>
__global__ __launch_bounds__(256) void k_gemm(
    const h16* __restrict__ A,
    const float* __restrict__ Atext, const float* __restrict__ Aimg,
    const float* __restrict__ muv, const float* __restrict__ rsd,
    const float* __restrict__ g, const float* __restrict__ be,
    const h16* __restrict__ BTt, const h16* __restrict__ BTi,
    const float* __restrict__ bias_t, const float* __restrict__ bias_i,
    h16* __restrict__ out,
    const int* __restrict__ tlen, const int* __restrict__ ilen,
    int omode)
{
  __shared__ __align__(16) h16 As[64*LDSK];
  __shared__ __align__(16) h16 Bs[64*LDSK];
  int n0 = blockIdx.x * 64;
  int m0 = blockIdx.y * 64;
  bool isimg = (m0 & 511) >= 384;               // 64-row tiles never straddle 384
  const h16* BT = isimg ? BTi : BTt;
  int t = threadIdx.x;
  int lane = t & 63, wid = t >> 6;
  int wm = wid >> 1, wn = wid & 1;
  int lg = lane >> 4, li = lane & 15;
  int sr = t >> 3, sc = (t & 7) * 8;
  f32x4 acc[2][2] = {};
  for (int kt = 0; kt < 768; kt += 64) {
    int d = kt + sc;
    #pragma unroll
    for (int half = 0; half < 2; ++half) {
      int r = sr + half*32;
      int gr = m0 + r;
      if constexpr (AMODE == 0) {
        *(uint4*)&As[r*LDSK + sc] = *(const uint4*)&A[(size_t)gr*768 + d];
      } else if constexpr (AMODE == 1) {
        int b = gr >> 9, l = gr & 511;
        const float* src = (l < 384) ? Atext + ((size_t)b*384 + l)*768
                                     : Aimg  + ((size_t)b*128 + (l-384))*768;
        float mu = muv[gr], rs = rsd[gr];
        f32x4 x0 = *(const f32x4*)&src[d], x1 = *(const f32x4*)&src[d+4];
        f32x4 g0 = *(const f32x4*)&g[d],   g1 = *(const f32x4*)&g[d+4];
        f32x4 e0 = *(const f32x4*)&be[d],  e1 = *(const f32x4*)&be[d+4];
        h16x8 o;
        #pragma unroll
        for (int j = 0; j < 4; ++j) o[j]   = (h16)((x0[j]-mu)*rs*g0[j] + e0[j]);
        #pragma unroll
        for (int j = 0; j < 4; ++j) o[4+j] = (h16)((x1[j]-mu)*rs*g1[j] + e1[j]);
        *(h16x8*)&As[r*LDSK + sc] = o;
      } else {
        int b = gr >> 9, l = gr & 511;
        int hd = d >= 384;
        *(uint4*)&As[r*LDSK + sc] =
          *(const uint4*)&A[(((size_t)(hd*64 + b))*512 + l)*384 + d - hd*384];
      }
      *(uint4*)&Bs[r*LDSK + sc] = *(const uint4*)&BT[(size_t)(n0+r)*768 + d];
    }
    __syncthreads();
    #pragma unroll
    for (int ks = 0; ks < 2; ++ks) {
      int kc = ks*32 + lg*8;
      h16x8 a0 = *(const h16x8*)&As[(wm*32      + li)*LDSK + kc];
      h16x8 a1 = *(const h16x8*)&As[(wm*32 + 16 + li)*LDSK + kc];
      h16x8 b0 = *(const h16x8*)&Bs[(wn*32      + li)*LDSK + kc];
      h16x8 b1 = *(const h16x8*)&Bs[(wn*32 + 16 + li)*LDSK + kc];
      acc[0][0] = MFMA(a0, b0, acc[0][0]);
      acc[0][1] = MFMA(a0, b1, acc[0][1]);
      acc[1][0] = MFMA(a1, b0, acc[1][0]);
      acc[1][1] = MFMA(a1, b1, acc[1][1]);
    }
    __syncthreads();
  }
  #pragma unroll
  for (int m = 0; m < 2; ++m)
    #pragma unroll
    for (int n = 0; n < 2; ++n)
      #pragma unroll
      for (int r = 0; r < 4; ++r) {
        int gr = m0 + wm*32 + m*16 + lg*4 + r;   // C row = (lane>>4)*4+reg
        int gc = n0 + wn*32 + n*16 + li;         // C col = lane&15
        int b = gr >> 9, l = gr & 511;
        float bv = (l < 384) ? bias_t[gc] : bias_i[gc];
        float v = acc[m][n][r] + bv;
        bool pad = (l < 384) ? (l >= tlen[b]) : ((l-384) >= ilen[b]);
        if (pad) v = 0.0f;
        size_t oi;
        if (omode == 0) {
          int h = (gc >= 384) ? 1 : 0;
          int kk = gc - h*384;
          oi = (((size_t)(h*64 + b))*512 + l)*384 + kk;
        } else {
          oi = (size_t)gr*768 + gc;
        }
        out[oi] = (h16)v;
      }
}

// ---------------- attention stage 1: per (h,b), 32 q-rows per block
// Output written IN-PLACE over Qb (Q layout): safe, block owns its 32 rows.
__global__ __launch_bounds__(256) void k_attn1(
    h16* Qb, const h16* __restrict__ Kb, const h16* __restrict__ Vb)
{
  __shared__ __align__(16) float S[32*516];
  __shared__ __align__(16) h16 VT[384*40];
  __shared__ float rowscale[32];
  int hb = blockIdx.y;
  int q0 = blockIdx.x * 32;
  h16* Qp = Qb + (size_t)hb * 512 * 384;
  const h16* Kp = Kb + (size_t)hb * 512 * 384;
  const h16* Vp = Vb + (size_t)hb * 512 * 384;
  int t = threadIdx.x, lane = t & 63, w = t >> 6;
  int lg = lane >> 4, li = lane & 15;

  // Q fragments in registers: 2 m-frags x 12 k-steps
  h16x8 aq[2][12];
  #pragma unroll
  for (int m = 0; m < 2; ++m)
    #pragma unroll
    for (int ks = 0; ks < 12; ++ks)
      aq[m][ks] = *(const h16x8*)&Qp[(size_t)(q0 + m*16 + li)*384 + ks*32 + lg*8];

  // scores: wave w owns keys [w*128, w*128+128)
  int kbase = w * 128;
  for (int nf = 0; nf < 8; ++nf) {
    int kcol = kbase + nf*16;
    f32x4 acc0 = {0,0,0,0}, acc1 = {0,0,0,0};
    #pragma unroll
    for (int ks = 0; ks < 12; ++ks) {
      h16x8 bk = *(const h16x8*)&Kp[(size_t)(kcol + li)*384 + ks*32 + lg*8];
      acc0 = MFMA(aq[0][ks], bk, acc0);
      acc1 = MFMA(aq[1][ks], bk, acc1);
    }
    #pragma unroll
    for (int r = 0; r < 4; ++r) {
      int c = kcol + li;
      int row0 = lg*4 + r;
      float v0 = acc0[r];
      if (v0 == 0.0f || (q0 + row0) == c) v0 = -__builtin_inff();
      S[row0*516 + c] = v0;
      int row1 = 16 + lg*4 + r;
      float v1 = acc1[r];
      if (v1 == 0.0f || (q0 + row1) == c) v1 = -__builtin_inff();
      S[row1*516 + c] = v1;
    }
  }
  __syncthreads();
  // masked softmax: 8 threads per row, strided cols
  {
    int row = t >> 3, ci = t & 7;
    float mx = -3e38f;
    for (int j = 0; j < 64; ++j) mx = fmaxf(mx, S[row*516 + ci + j*8]);
    mx = fmaxf(mx, __shfl_xor(mx, 1));
    mx = fmaxf(mx, __shfl_xor(mx, 2));
    mx = fmaxf(mx, __shfl_xor(mx, 4));
    float sum = 0.0f;
    for (int j = 0; j < 64; ++j) {
      float e = __expf(S[row*516 + ci + j*8] - mx);  // exp(-inf)=0 handles masked
      S[row*516 + ci + j*8] = e;
      sum += e;
    }
    sum += __shfl_xor(sum, 1);
    sum += __shfl_xor(sum, 2);
    sum += __shfl_xor(sum, 4);
    if (ci == 0) rowscale[row] = 1.0f / (sum > 0.0f ? sum : 1.0f);
  }
  __syncthreads();
  // PV: wave w owns v-cols [w*96, w*96+96)
  f32x4 oacc[2][6] = {};
  int v0w = w * 96;
  for (int kt = 0; kt < 16; ++kt) {
    if (kt) __syncthreads();
    for (int c = t; c < 1536; c += 256) {      // stage V^T tile (32 kk x 384 v)
      int kk = c / 48, vv = (c % 48) * 8;
      h16x8 v8 = *(const h16x8*)&Vp[(size_t)(kt*32 + kk)*384 + vv];
      #pragma unroll
      for (int j = 0; j < 8; ++j) VT[(vv+j)*40 + kk] = v8[j];
    }
    __syncthreads();
    #pragma unroll
    for (int m = 0; m < 2; ++m) {
      int row = m*16 + li;
      float scl = rowscale[row];
      f32x4 p0 = *(const f32x4*)&S[row*516 + kt*32 + lg*8];
      f32x4 p1 = *(const f32x4*)&S[row*516 + kt*32 + lg*8 + 4];
      h16x8 pa;
      pa[0]=(h16)(p0[0]*scl); pa[1]=(h16)(p0[1]*scl);
      pa[2]=(h16)(p0[2]*scl); pa[3]=(h16)(p0[3]*scl);
      pa[4]=(h16)(p1[0]*scl); pa[5]=(h16)(p1[1]*scl);
      pa[6]=(h16)(p1[2]*scl); pa[7]=(h16)(p1[3]*scl);
      #pragma unroll
      for (int n = 0; n < 6; ++n) {
        h16x8 bv = *(const h16x8*)&VT[(v0w + n*16 + li)*40 + lg*8];
        oacc[m][n] = MFMA(pa, bv, oacc[m][n]);
      }
    }
  }
  #pragma unroll
  for (int m = 0; m < 2; ++m)
    #pragma unroll
    for (int n = 0; n < 6; ++n)
      #pragma unroll
      for (int r = 0; r < 4; ++r) {
        int row = m*16 + lg*4 + r;
        int col = v0w + n*16 + li;
        Qp[(size_t)(q0 + row)*384 + col] = (h16)oacc[m][n][r];
      }
}

// ---------------- attention stage 2 + mean: one block per b
__global__ __launch_bounds__(256) void k_attn2(
    const float* __restrict__ query, const h16* __restrict__ keys,
    const h16* __restrict__ vals, const int* __restrict__ qlen,
    float* __restrict__ out)
{
  __shared__ __align__(16) float S[32*516];
  __shared__ __align__(16) h16 UB[32*776];   // qf (score phase) then V^T (PV phase)
  __shared__ float rowscale[32];
  int b = blockIdx.x;
  const float* Qp = query + (size_t)b*24*768;
  const h16* Kp = keys + (size_t)b*512*768;
  const h16* Vp = vals + (size_t)b*512*768;
  int t = threadIdx.x, lane = t & 63, w = t >> 6;
  int lg = lane >> 4, li = lane & 15;
  int ql = qlen[b];
  // stage masked query rows (0..31; >=24 or >=ql zeroed) as fp16
  for (int c = t; c < 3072; c += 256) {
    int row = c / 96, vv = (c % 96) * 8;
    h16x8 a = {};
    if (row < 24 && row < ql) {
      f32x4 f0 = *(const f32x4*)&Qp[(size_t)row*768 + vv];
      f32x4 f1 = *(const f32x4*)&Qp[(size_t)row*768 + vv + 4];
      a[0]=(h16)f0[0]; a[1]=(h16)f0[1]; a[2]=(h16)f0[2]; a[3]=(h16)f0[3];
      a[4]=(h16)f1[0]; a[5]=(h16)f1[1]; a[6]=(h16)f1[2]; a[7]=(h16)f1[3];
    }
    *(h16x8*)&UB[row*776 + vv] = a;
  }
  __syncthreads();
  int kbase = w * 128;
  for (int nf = 0; nf < 8; ++nf) {
    int kcol = kbase + nf*16;
    f32x4 acc0 = {0,0,0,0}, acc1 = {0,0,0,0};
    #pragma unroll
    for (int ks = 0; ks < 24; ++ks) {
      h16x8 a0 = *(const h16x8*)&UB[(li)*776      + ks*32 + lg*8];
      h16x8 a1 = *(const h16x8*)&UB[(16 + li)*776 + ks*32 + lg*8];
      h16x8 bk = *(const h16x8*)&Kp[(size_t)(kcol + li)*768 + ks*32 + lg*8];
      acc0 = MFMA(a0, bk, acc0);
      acc1 = MFMA(a1, bk, acc1);
    }
    #pragma unroll
    for (int r = 0; r < 4; ++r) {
      int c = kcol + li;
      float v0 = acc0[r];
      if (v0 == 0.0f) v0 = -__builtin_inff();
      S[(lg*4 + r)*516 + c] = v0;
      float v1 = acc1[r];
      if (v1 == 0.0f) v1 = -__builtin_inff();
      S[(16 + lg*4 + r)*516 + c] = v1;
    }
  }
  __syncthreads();
  {
    int row = t >> 3, ci = t & 7;
    float mx = -3e38f;
    for (int j = 0; j < 64; ++j) mx = fmaxf(mx, S[row*516 + ci + j*8]);
    mx = fmaxf(mx, __shfl_xor(mx, 1));
    mx = fmaxf(mx, __shfl_xor(mx, 2));
    mx = fmaxf(mx, __shfl_xor(mx, 4));
    float sum = 0.0f;
    for (int j = 0; j < 64; ++j) {
      float e = __expf(S[row*516 + ci + j*8] - mx);
      S[row*516 + ci + j*8] = e;
      sum += e;
    }
    sum += __shfl_xor(sum, 1);
    sum += __shfl_xor(sum, 2);
    sum += __shfl_xor(sum, 4);
    if (ci == 0) rowscale[row] = 1.0f / (sum > 0.0f ? sum : 1.0f);
  }
  __syncthreads();
  h16* VT = UB;
  for (int vh = 0; vh < 2; ++vh) {
    f32x4 oacc[2][6] = {};
    for (int kt = 0; kt < 16; ++kt) {
      __syncthreads();
      for (int c = t; c < 1536; c += 256) {
        int kk = c / 48, vv = (c % 48) * 8;
        h16x8 v8 = *(const h16x8*)&Vp[(size_t)(kt*32 + kk)*768 + vh*384 + vv];
        #pragma unroll
        for (int j = 0; j < 8; ++j) VT[(vv+j)*40 + kk] = v8[j];
      }
      __syncthreads();
      #pragma unroll
      for (int m = 0; m < 2; ++m) {
        int row = m*16 + li;
        float scl = rowscale[row];
        f32x4 p0 = *(const f32x4*)&S[row*516 + kt*32 + lg*8];
        f32x4 p1 = *(const f32x4*)&S[row*516 + kt*32 + lg*8 + 4];
        h16x8 pa;
        pa[0]=(h16)(p0[0]*scl); pa[1]=(h16)(p0[1]*scl);
        pa[2]=(h16)(p0[2]*scl); pa[3]=(h16)(p0[3]*scl);
        pa[4]=(h16)(p1[0]*scl); pa[5]=(h16)(p1[1]*scl);
        pa[6]=(h16)(p1[2]*scl); pa[7]=(h16)(p1[3]*scl);
        #pragma unroll
        for (int n = 0; n < 6; ++n) {
          h16x8 bv = *(const h16x8*)&VT[(w*96 + n*16 + li)*40 + lg*8];
          oacc[m][n] = MFMA(pa, bv, oacc[m][n]);
        }
      }
    }
    #pragma unroll
    for (int n = 0; n < 6; ++n) {
      float cs = 0.0f;
      #pragma unroll
      for (int m = 0; m < 2; ++m)
        #pragma unroll
        for (int r = 0; r < 4; ++r) cs += oacc[m][n][r];
      cs += __shfl_xor(cs, 16);
      cs += __shfl_xor(cs, 32);
      if (lg == 0) out[(size_t)b*768 + vh*384 + w*96 + n*16 + li] = cs * (1.0f/24.0f);
    }
  }
}

extern "C" void kernel_launch(void* const* d_in, const int* in_sizes, int n_in,
                              void* d_out, int out_size, void* d_ws, size_t ws_size,
                              hipStream_t stream)
{
  (void)in_sizes; (void)n_in;
  const float* text  = (const float*)d_in[0];
  const float* images= (const float*)d_in[1];
  const float* query = (const float*)d_in[2];
  const float* ln_g  = (const float*)d_in[3];
  const float* ln_b  = (const float*)d_in[4];
  const float* Wsq = (const float*)d_in[5];
  const float* bsq = (const float*)d_in[6];
  const float* Wiq = (const float*)d_in[7];
  const float* biq = (const float*)d_in[8];
  const float* Wsk = (const float*)d_in[9];
  const float* bsk = (const float*)d_in[10];
  const float* Wik = (const float*)d_in[11];
  const float* bik = (const float*)d_in[12];
  const float* Wsv = (const float*)d_in[13];
  const float* bsv = (const float*)d_in[14];
  const float* Wiv = (const float*)d_in[15];
  const float* biv = (const float*)d_in[16];
  const float* Wkp = (const float*)d_in[17];
  const float* bkp = (const float*)d_in[18];
  const float* Wvp = (const float*)d_in[19];
  const float* bvp = (const float*)d_in[20];
  const int* tlen = (const int*)d_in[21];
  const int* ilen = (const int*)d_in[22];
  const int* qlen = (const int*)d_in[23];

  // workspace layout (total 160,694,272 bytes):
  //   [0, 256KB)        : mu[32768], rstd[32768] (f32)
  //   [256KB, +9.4MB)   : 8 transposed fp16 weight buffers (768x768 each)
  //   3 x 50.33MB       : Qb (->album), Kb (->keys), Vb (XN -> V -> vals)
  const size_t NEED = 160694272;
  if (ws_size < NEED) {
    k_diag<<<dim3((out_size+255)/256), dim3(256), 0, stream>>>((float*)d_out, out_size, 1.0e6f);
    return;
  }
  float* muv = (float*)d_ws;
  float* rsd = muv + 32768;
  h16* wb = (h16*)((char*)d_ws + 262144);
  const size_t WSZ = 589824;                 // 768*768 elements
  h16* WQ_T = wb;            h16* WQ_I = wb + WSZ;
  h16* WK_T = wb + 2*WSZ;    h16* WK_I = wb + 3*WSZ;
  h16* WV_T = wb + 4*WSZ;    h16* WV_I = wb + 5*WSZ;
  h16* WKP  = wb + 6*WSZ;    h16* WVP  = wb + 7*WSZ;
  const size_t TSZ = (size_t)32768*768;      // 25165824 elements
  h16* Qb = wb + 8*WSZ;
  h16* Kb = Qb + TSZ;
  h16* Vb = Kb + TSZ;                        // holds XN first, then V, then vals

  dim3 blk(256);
  k_wprep<<<dim3(12,24,2), blk, 0, stream>>>(Wsq, WQ_T, 384);
  k_wprep<<<dim3(12,24,2), blk, 0, stream>>>(Wiq, WQ_I, 384);
  k_wprep<<<dim3(12,24,2), blk, 0, stream>>>(Wsk, WK_T, 384);
  k_wprep<<<dim3(12,24,2), blk, 0, stream>>>(Wik, WK_I, 384);
  k_wprep<<<dim3(12,24,2), blk, 0, stream>>>(Wsv, WV_T, 384);
  k_wprep<<<dim3(12,24,2), blk, 0, stream>>>(Wiv, WV_I, 384);
  k_wprep<<<dim3(24,24,1), blk, 0, stream>>>(Wkp, WKP, 768);
  k_wprep<<<dim3(24,24,1), blk, 0, stream>>>(Wvp, WVP, 768);

  // LN -> XN stored in Vb, plus row stats
  k_ln<<<dim3(32768), blk, 0, stream>>>(text, images, ln_g, ln_b, Vb, muv, rsd);

  // Q, K projections read XN@Vb
  k_gemm<0><<<dim3(12,512), blk, 0, stream>>>(Vb, nullptr, nullptr, nullptr, nullptr,
      nullptr, nullptr, WQ_T, WQ_I, bsq, biq, Qb, tlen, ilen, 0);
  k_gemm<0><<<dim3(12,512), blk, 0, stream>>>(Vb, nullptr, nullptr, nullptr, nullptr,
      nullptr, nullptr, WK_T, WK_I, bsk, bik, Kb, tlen, ilen, 0);
  // V projection: LN on the fly from f32 inputs, overwrites XN@Vb
  k_gemm<1><<<dim3(12,512), blk, 0, stream>>>(nullptr, text, images, muv, rsd,
      ln_g, ln_b, WV_T, WV_I, bsv, biv, Vb, tlen, ilen, 0);

  // attention stage 1: album written in-place over Qb (Q layout)
  k_attn1<<<dim3(16,128), blk, 0, stream>>>(Qb, Kb, Vb);

  // keys/vals projections read album@Qb (head-split layout), write over Kb/Vb
  k_gemm<2><<<dim3(12,512), blk, 0, stream>>>(Qb, nullptr, nullptr, nullptr, nullptr,
      nullptr, nullptr, WKP, WKP, bkp, bkp, Kb, tlen, ilen, 1);
  k_gemm<2><<<dim3(12,512), blk, 0, stream>>>(Qb, nullptr, nullptr, nullptr, nullptr,
      nullptr, nullptr, WVP, WVP, bvp, bvp, Vb, tlen, ilen, 1);

  k_attn2<<<dim3(64), blk, 0, stream>>>(query, Kb, Vb, qlen, (float*)d_out);
}

// Round 4
// 942.014 us; speedup vs baseline: 1.7611x; 1.7611x over previous
//
#include <hip/hip_runtime.h>
#include <hip/hip_bf16.h>

typedef _Float16 h16;
typedef _Float16 h16x8 __attribute__((ext_vector_type(8)));
typedef float    f32x4 __attribute__((ext_vector_type(4)));

#define MFMA(a,b,c) __builtin_amdgcn_mfma_f32_16x16x32_f16((a),(b),(c),0,0,0)

// H=2 B=64 LT=384 LI=128 L=512 D=768 K=V=384 DK=DV=768 LQ=24

__global__ __launch_bounds__(256) void k_diag(float* out, int n, float val) {
  int i = blockIdx.x * 256 + threadIdx.x;
  if (i < n) out[i] = val;
}

// ---------------- LayerNorm -> fp16 xn[b*512+l][768]  + per-row stats
__global__ __launch_bounds__(256) void k_ln(
    const float* __restrict__ text, const float* __restrict__ images,
    const float* __restrict__ g, const float* __restrict__ be,
    h16* __restrict__ xn, float* __restrict__ muv, float* __restrict__ rsd)
{
  int row = blockIdx.x;
  int b = row >> 9, l = row & 511;
  const float* src = (l < 384) ? (text + ((size_t)b*384 + l)*768)
                               : (images + ((size_t)b*128 + (l-384))*768);
  int t = threadIdx.x;
  float x0 = src[t], x1 = src[t+256], x2 = src[t+512];
  __shared__ float red[8];
  float s = x0 + x1 + x2;
  #pragma unroll
  for (int m = 32; m; m >>= 1) s += __shfl_xor(s, m);
  int wid = t >> 6;
  if ((t & 63) == 0) red[wid] = s;
  __syncthreads();
  float mu = (red[0]+red[1]+red[2]+red[3]) * (1.0f/768.0f);
  float d0 = x0-mu, d1 = x1-mu, d2 = x2-mu;
  float v = d0*d0 + d1*d1 + d2*d2;
  #pragma unroll
  for (int m = 32; m; m >>= 1) v += __shfl_xor(v, m);
  if ((t & 63) == 0) red[4+wid] = v;
  __syncthreads();
  float var = (red[4]+red[5]+red[6]+red[7]) * (1.0f/768.0f);
  float rstd = rsqrtf(var + 1e-5f);
  if (t == 0) { muv[row] = mu; rsd[row] = rstd; }
  h16* dst = xn + (size_t)row * 768;
  dst[t]     = (h16)(d0*rstd*g[t]     + be[t]);
  dst[t+256] = (h16)(d1*rstd*g[t+256] + be[t+256]);
  dst[t+512] = (h16)(d2*rstd*g[t+512] + be[t+512]);
}

// ---------------- weight prep: src (nmat,768,cols) f32 -> dst (nmat,cols,768) fp16
__global__ __launch_bounds__(256) void k_wprep(
    const float* __restrict__ src, h16* __restrict__ dst, int cols)
{
  __shared__ float tile[32][33];
  int m = blockIdx.z;
  int d0 = blockIdx.y * 32;
  int c0 = blockIdx.x * 32;
  const float* s = src + (size_t)m * 768 * cols;
  h16* dd = dst + (size_t)m * cols * 768;
  int tx = threadIdx.x & 31, ty = threadIdx.x >> 5;
  #pragma unroll
  for (int i = 0; i < 32; i += 8)
    tile[ty+i][tx] = s[(size_t)(d0+ty+i)*cols + c0 + tx];
  __syncthreads();
  #pragma unroll
  for (int i = 0; i < 32; i += 8)
    dd[(size_t)(c0+ty+i)*768 + d0 + tx] = (h16)tile[tx][ty+i];
}

// ---------------- GEMM: C[32768 x 768] = A[32768 x 768] x BT^T (+bias, pad-zero)
// AMODE 0: A = fp16 [gr][768]
// AMODE 1: A = LN(text/images) on the fly (f32 src + stats)
// AMODE 2: A = album stored in Q-layout: (h*64+b, l, c) head-split at d=384
// omode 0: out[((h*64+b)*512+l)*384+kk]     (Q,K proj)
// omode 1: out[(b*512+l)*768+n]             (keys)
// omode 2: out[((h*64+b)*384+kk)*512+l]     (V proj, transposed)
// omode 3: out[(b*768+n)*512+l]             (vals, transposed)
#define LDSK 72
template<int AMODE>
__global__ __launch_bounds__(256) void k_gemm(
    const h16* __restrict__ A,
    const float* __restrict__ Atext, const float* __restrict__ Aimg,
    const float* __restrict__ muv, const float* __restrict__ rsd,
    const float* __restrict__ g, const float* __restrict__ be,
    const h16* __restrict__ BTt, const h16* __restrict__ BTi,
    const float* __restrict__ bias_t, const float* __restrict__ bias_i,
    h16* __restrict__ out,
    const int* __restrict__ tlen, const int* __restrict__ ilen,
    int omode)
{
  __shared__ __align__(16) h16 As[64*LDSK];
  __shared__ __align__(16) h16 Bs[64*LDSK];
  int n0 = blockIdx.x * 64;
  int m0 = blockIdx.y * 64;
  bool isimg = (m0 & 511) >= 384;               // 64-row tiles never straddle 384
  const h16* BT = isimg ? BTi : BTt;
  int t = threadIdx.x;
  int lane = t & 63, wid = t >> 6;
  int wm = wid >> 1, wn = wid & 1;
  int lg = lane >> 4, li = lane & 15;
  int sr = t >> 3, sc = (t & 7) * 8;
  f32x4 acc[2][2] = {};
  for (int kt = 0; kt < 768; kt += 64) {
    int d = kt + sc;
    #pragma unroll
    for (int half = 0; half < 2; ++half) {
      int r = sr + half*32;
      int gr = m0 + r;
      if constexpr (AMODE == 0) {
        *(uint4*)&As[r*LDSK + sc] = *(const uint4*)&A[(size_t)gr*768 + d];
      } else if constexpr (AMODE == 1) {
        int b = gr >> 9, l = gr & 511;
        const float* src = (l < 384) ? Atext + ((size_t)b*384 + l)*768
                                     : Aimg  + ((size_t)b*128 + (l-384))*768;
        float mu = muv[gr], rs = rsd[gr];
        f32x4 x0 = *(const f32x4*)&src[d], x1 = *(const f32x4*)&src[d+4];
        f32x4 g0 = *(const f32x4*)&g[d],   g1 = *(const f32x4*)&g[d+4];
        f32x4 e0 = *(const f32x4*)&be[d],  e1 = *(const f32x4*)&be[d+4];
        h16x8 o;
        #pragma unroll
        for (int j = 0; j < 4; ++j) o[j]   = (h16)((x0[j]-mu)*rs*g0[j] + e0[j]);
        #pragma unroll
        for (int j = 0; j < 4; ++j) o[4+j] = (h16)((x1[j]-mu)*rs*g1[j] + e1[j]);
        *(h16x8*)&As[r*LDSK + sc] = o;
      } else {
        int b = gr >> 9, l = gr & 511;
        int hd = d >= 384;
        *(uint4*)&As[r*LDSK + sc] =
          *(const uint4*)&A[(((size_t)(hd*64 + b))*512 + l)*384 + d - hd*384];
      }
      *(uint4*)&Bs[r*LDSK + sc] = *(const uint4*)&BT[(size_t)(n0+r)*768 + d];
    }
    __syncthreads();
    #pragma unroll
    for (int ks = 0; ks < 2; ++ks) {
      int kc = ks*32 + lg*8;
      h16x8 a0 = *(const h16x8*)&As[(wm*32      + li)*LDSK + kc];
      h16x8 a1 = *(const h16x8*)&As[(wm*32 + 16 + li)*LDSK + kc];
      h16x8 b0 = *(const h16x8*)&Bs[(wn*32      + li)*LDSK + kc];
      h16x8 b1 = *(const h16x8*)&Bs[(wn*32 + 16 + li)*LDSK + kc];
      acc[0][0] = MFMA(a0, b0, acc[0][0]);
      acc[0][1] = MFMA(a0, b1, acc[0][1]);
      acc[1][0] = MFMA(a1, b0, acc[1][0]);
      acc[1][1] = MFMA(a1, b1, acc[1][1]);
    }
    __syncthreads();
  }
  #pragma unroll
  for (int m = 0; m < 2; ++m)
    #pragma unroll
    for (int n = 0; n < 2; ++n)
      #pragma unroll
      for (int r = 0; r < 4; ++r) {
        int gr = m0 + wm*32 + m*16 + lg*4 + r;   // C row = (lane>>4)*4+reg
        int gc = n0 + wn*32 + n*16 + li;         // C col = lane&15
        int b = gr >> 9, l = gr & 511;
        float bv = (l < 384) ? bias_t[gc] : bias_i[gc];
        float v = acc[m][n][r] + bv;
        bool pad = (l < 384) ? (l >= tlen[b]) : ((l-384) >= ilen[b]);
        if (pad) v = 0.0f;
        size_t oi;
        if (omode == 0) {
          int h = (gc >= 384) ? 1 : 0;
          int kk = gc - h*384;
          oi = (((size_t)(h*64 + b))*512 + l)*384 + kk;
        } else if (omode == 1) {
          oi = (size_t)gr*768 + gc;
        } else if (omode == 2) {
          int h = (gc >= 384) ? 1 : 0;
          int kk = gc - h*384;
          oi = (((size_t)(h*64 + b))*384 + kk)*512 + l;
        } else {
          oi = ((size_t)b*768 + gc)*512 + l;
        }
        out[oi] = (h16)v;
      }
}

// ---------------- attention stage 1: per (h,b), 32 q-rows per block
// V supplied TRANSPOSED (Vt[hb][vcol][l]); PV reads B-frags from global.
// Output written IN-PLACE over Qb (Q layout): safe, block owns its 32 rows.
__global__ __launch_bounds__(256) void k_attn1(
    h16* Qb, const h16* __restrict__ Kb, const h16* __restrict__ Vt)
{
  __shared__ __align__(16) float S[32*516];
  __shared__ float rowscale[32];
  int hb = blockIdx.y;
  int q0 = blockIdx.x * 32;
  h16* Qp = Qb + (size_t)hb * 512 * 384;
  const h16* Kp = Kb + (size_t)hb * 512 * 384;
  const h16* Vp = Vt + (size_t)hb * 384 * 512;
  int t = threadIdx.x, lane = t & 63, w = t >> 6;
  int lg = lane >> 4, li = lane & 15;

  // Q fragments in registers: 2 m-frags x 12 k-steps
  h16x8 aq[2][12];
  #pragma unroll
  for (int m = 0; m < 2; ++m)
    #pragma unroll
    for (int ks = 0; ks < 12; ++ks)
      aq[m][ks] = *(const h16x8*)&Qp[(size_t)(q0 + m*16 + li)*384 + ks*32 + lg*8];

  // scores: wave w owns keys [w*128, w*128+128)
  int kbase = w * 128;
  for (int nf = 0; nf < 8; ++nf) {
    int kcol = kbase + nf*16;
    f32x4 acc0 = {0,0,0,0}, acc1 = {0,0,0,0};
    #pragma unroll
    for (int ks = 0; ks < 12; ++ks) {
      h16x8 bk = *(const h16x8*)&Kp[(size_t)(kcol + li)*384 + ks*32 + lg*8];
      acc0 = MFMA(aq[0][ks], bk, acc0);
      acc1 = MFMA(aq[1][ks], bk, acc1);
    }
    #pragma unroll
    for (int r = 0; r < 4; ++r) {
      int c = kcol + li;
      int row0 = lg*4 + r;
      float v0 = acc0[r];
      if (v0 == 0.0f || (q0 + row0) == c) v0 = -__builtin_inff();
      S[row0*516 + c] = v0;
      int row1 = 16 + lg*4 + r;
      float v1 = acc1[r];
      if (v1 == 0.0f || (q0 + row1) == c) v1 = -__builtin_inff();
      S[row1*516 + c] = v1;
    }
  }
  __syncthreads();
  // masked softmax: 8 threads per row; P stored UNNORMALIZED (scale at epilogue)
  {
    int row = t >> 3, ci = t & 7;
    float mx = -3e38f;
    for (int j = 0; j < 64; ++j) mx = fmaxf(mx, S[row*516 + ci + j*8]);
    mx = fmaxf(mx, __shfl_xor(mx, 1));
    mx = fmaxf(mx, __shfl_xor(mx, 2));
    mx = fmaxf(mx, __shfl_xor(mx, 4));
    float sum = 0.0f;
    for (int j = 0; j < 64; ++j) {
      float e = __expf(S[row*516 + ci + j*8] - mx);  // exp(-inf)=0 handles masked
      S[row*516 + ci + j*8] = e;
      sum += e;
    }
    sum += __shfl_xor(sum, 1);
    sum += __shfl_xor(sum, 2);
    sum += __shfl_xor(sum, 4);
    if (ci == 0) rowscale[row] = 1.0f / (sum > 0.0f ? sum : 1.0f);
  }
  __syncthreads();
  // PV: wave w owns v-cols [w*96, w*96+96); B-frags straight from global Vt
  f32x4 oacc[2][6] = {};
  int v0w = w * 96;
  for (int kt = 0; kt < 16; ++kt) {
    h16x8 bv[6];
    #pragma unroll
    for (int n = 0; n < 6; ++n)
      bv[n] = *(const h16x8*)&Vp[(size_t)(v0w + n*16 + li)*512 + kt*32 + lg*8];
    #pragma unroll
    for (int m = 0; m < 2; ++m) {
      int row = m*16 + li;
      f32x4 p0 = *(const f32x4*)&S[row*516 + kt*32 + lg*8];
      f32x4 p1 = *(const f32x4*)&S[row*516 + kt*32 + lg*8 + 4];
      h16x8 pa;
      pa[0]=(h16)p0[0]; pa[1]=(h16)p0[1]; pa[2]=(h16)p0[2]; pa[3]=(h16)p0[3];
      pa[4]=(h16)p1[0]; pa[5]=(h16)p1[1]; pa[6]=(h16)p1[2]; pa[7]=(h16)p1[3];
      #pragma unroll
      for (int n = 0; n < 6; ++n)
        oacc[m][n] = MFMA(pa, bv[n], oacc[m][n]);
    }
  }
  #pragma unroll
  for (int m = 0; m < 2; ++m)
    #pragma unroll
    for (int n = 0; n < 6; ++n)
      #pragma unroll
      for (int r = 0; r < 4; ++r) {
        int row = m*16 + lg*4 + r;
        int col = v0w + n*16 + li;
        Qp[(size_t)(q0 + row)*384 + col] = (h16)(oacc[m][n][r] * rowscale[row]);
      }
}

// ---------------- attention stage 2 + mean: one block per b
// vals supplied TRANSPOSED (valsT[b][v][l]).
__global__ __launch_bounds__(256) void k_attn2(
    const float* __restrict__ query, const h16* __restrict__ keys,
    const h16* __restrict__ valsT, const int* __restrict__ qlen,
    float* __restrict__ out)
{
  __shared__ __align__(16) float S[32*516];
  __shared__ __align__(16) h16 UB[32*776];   // masked fp16 query rows
  __shared__ float rowscale[32];
  int b = blockIdx.x;
  const float* Qp = query + (size_t)b*24*768;
  const h16* Kp = keys + (size_t)b*512*768;
  const h16* Vp = valsT + (size_t)b*768*512;
  int t = threadIdx.x, lane = t & 63, w = t >> 6;
  int lg = lane >> 4, li = lane & 15;
  int ql = qlen[b];
  // stage masked query rows (0..31; >=24 or >=ql zeroed) as fp16
  for (int c = t; c < 3072; c += 256) {
    int row = c / 96, vv = (c % 96) * 8;
    h16x8 a = {};
    if (row < 24 && row < ql) {
      f32x4 f0 = *(const f32x4*)&Qp[(size_t)row*768 + vv];
      f32x4 f1 = *(const f32x4*)&Qp[(size_t)row*768 + vv + 4];
      a[0]=(h16)f0[0]; a[1]=(h16)f0[1]; a[2]=(h16)f0[2]; a[3]=(h16)f0[3];
      a[4]=(h16)f1[0]; a[5]=(h16)f1[1]; a[6]=(h16)f1[2]; a[7]=(h16)f1[3];
    }
    *(h16x8*)&UB[row*776 + vv] = a;
  }
  __syncthreads();
  int kbase = w * 128;
  for (int nf = 0; nf < 8; ++nf) {
    int kcol = kbase + nf*16;
    f32x4 acc0 = {0,0,0,0}, acc1 = {0,0,0,0};
    #pragma unroll
    for (int ks = 0; ks < 24; ++ks) {
      h16x8 a0 = *(const h16x8*)&UB[(li)*776      + ks*32 + lg*8];
      h16x8 a1 = *(const h16x8*)&UB[(16 + li)*776 + ks*32 + lg*8];
      h16x8 bk = *(const h16x8*)&Kp[(size_t)(kcol + li)*768 + ks*32 + lg*8];
      acc0 = MFMA(a0, bk, acc0);
      acc1 = MFMA(a1, bk, acc1);
    }
    #pragma unroll
    for (int r = 0; r < 4; ++r) {
      int c = kcol + li;
      float v0 = acc0[r];
      if (v0 == 0.0f) v0 = -__builtin_inff();
      S[(lg*4 + r)*516 + c] = v0;
      float v1 = acc1[r];
      if (v1 == 0.0f) v1 = -__builtin_inff();
      S[(16 + lg*4 + r)*516 + c] = v1;
    }
  }
  __syncthreads();
  {
    int row = t >> 3, ci = t & 7;
    float mx = -3e38f;
    for (int j = 0; j < 64; ++j) mx = fmaxf(mx, S[row*516 + ci + j*8]);
    mx = fmaxf(mx, __shfl_xor(mx, 1));
    mx = fmaxf(mx, __shfl_xor(mx, 2));
    mx = fmaxf(mx, __shfl_xor(mx, 4));
    float sum = 0.0f;
    for (int j = 0; j < 64; ++j) {
      float e = __expf(S[row*516 + ci + j*8] - mx);
      S[row*516 + ci + j*8] = e;
      sum += e;
    }
    sum += __shfl_xor(sum, 1);
    sum += __shfl_xor(sum, 2);
    sum += __shfl_xor(sum, 4);
    if (ci == 0) rowscale[row] = 1.0f / (sum > 0.0f ? sum : 1.0f);
  }
  __syncthreads();
  for (int vh = 0; vh < 2; ++vh) {
    f32x4 oacc[2][6] = {};
    for (int kt = 0; kt < 16; ++kt) {
      h16x8 bv[6];
      #pragma unroll
      for (int n = 0; n < 6; ++n)
        bv[n] = *(const h16x8*)&Vp[(size_t)(vh*384 + w*96 + n*16 + li)*512 + kt*32 + lg*8];
      #pragma unroll
      for (int m = 0; m < 2; ++m) {
        int row = m*16 + li;
        f32x4 p0 = *(const f32x4*)&S[row*516 + kt*32 + lg*8];
        f32x4 p1 = *(const f32x4*)&S[row*516 + kt*32 + lg*8 + 4];
        h16x8 pa;
        pa[0]=(h16)p0[0]; pa[1]=(h16)p0[1]; pa[2]=(h16)p0[2]; pa[3]=(h16)p0[3];
        pa[4]=(h16)p1[0]; pa[5]=(h16)p1[1]; pa[6]=(h16)p1[2]; pa[7]=(h16)p1[3];
        #pragma unroll
        for (int n = 0; n < 6; ++n)
          oacc[m][n] = MFMA(pa, bv[n], oacc[m][n]);
      }
    }
    #pragma unroll
    for (int n = 0; n < 6; ++n) {
      float cs = 0.0f;
      #pragma unroll
      for (int m = 0; m < 2; ++m)
        #pragma unroll
        for (int r = 0; r < 4; ++r)
          cs += oacc[m][n][r] * rowscale[m*16 + lg*4 + r];
      cs += __shfl_xor(cs, 16);
      cs += __shfl_xor(cs, 32);
      if (lg == 0) out[(size_t)b*768 + vh*384 + w*96 + n*16 + li] = cs * (1.0f/24.0f);
    }
  }
}

extern "C" void kernel_launch(void* const* d_in, const int* in_sizes, int n_in,
                              void* d_out, int out_size, void* d_ws, size_t ws_size,
                              hipStream_t stream)
{
  (void)in_sizes; (void)n_in;
  const float* text  = (const float*)d_in[0];
  const float* images= (const float*)d_in[1];
  const float* query = (const float*)d_in[2];
  const float* ln_g  = (const float*)d_in[3];
  const float* ln_b  = (const float*)d_in[4];
  const float* Wsq = (const float*)d_in[5];
  const float* bsq = (const float*)d_in[6];
  const float* Wiq = (const float*)d_in[7];
  const float* biq = (const float*)d_in[8];
  const float* Wsk = (const float*)d_in[9];
  const float* bsk = (const float*)d_in[10];
  const float* Wik = (const float*)d_in[11];
  const float* bik = (const float*)d_in[12];
  const float* Wsv = (const float*)d_in[13];
  const float* bsv = (const float*)d_in[14];
  const float* Wiv = (const float*)d_in[15];
  const float* biv = (const float*)d_in[16];
  const float* Wkp = (const float*)d_in[17];
  const float* bkp = (const float*)d_in[18];
  const float* Wvp = (const float*)d_in[19];
  const float* bvp = (const float*)d_in[20];
  const int* tlen = (const int*)d_in[21];
  const int* ilen = (const int*)d_in[22];
  const int* qlen = (const int*)d_in[23];

  // workspace layout (total 160,694,272 bytes):
  //   [0, 256KB)        : mu[32768], rstd[32768] (f32)
  //   [256KB, +9.4MB)   : 8 transposed fp16 weight buffers (768x768 each)
  //   3 x 50.33MB       : Qb (->album), Kb (->keys), Vb (XN -> V^T -> vals^T)
  const size_t NEED = 160694272;
  if (ws_size < NEED) {
    k_diag<<<dim3((out_size+255)/256), dim3(256), 0, stream>>>((float*)d_out, out_size, 1.0e6f);
    return;
  }
  float* muv = (float*)d_ws;
  float* rsd = muv + 32768;
  h16* wb = (h16*)((char*)d_ws + 262144);
  const size_t WSZ = 589824;                 // 768*768 elements
  h16* WQ_T = wb;            h16* WQ_I = wb + WSZ;
  h16* WK_T = wb + 2*WSZ;    h16* WK_I = wb + 3*WSZ;
  h16* WV_T = wb + 4*WSZ;    h16* WV_I = wb + 5*WSZ;
  h16* WKP  = wb + 6*WSZ;    h16* WVP  = wb + 7*WSZ;
  const size_t TSZ = (size_t)32768*768;      // 25165824 elements
  h16* Qb = wb + 8*WSZ;
  h16* Kb = Qb + TSZ;
  h16* Vb = Kb + TSZ;                        // XN first, then V^T, then vals^T

  dim3 blk(256);
  k_wprep<<<dim3(12,24,2), blk, 0, stream>>>(Wsq, WQ_T, 384);
  k_wprep<<<dim3(12,24,2), blk, 0, stream>>>(Wiq, WQ_I, 384);
  k_wprep<<<dim3(12,24,2), blk, 0, stream>>>(Wsk, WK_T, 384);
  k_wprep<<<dim3(12,24,2), blk, 0, stream>>>(Wik, WK_I, 384);
  k_wprep<<<dim3(12,24,2), blk, 0, stream>>>(Wsv, WV_T, 384);
  k_wprep<<<dim3(12,24,2), blk, 0, stream>>>(Wiv, WV_I, 384);
  k_wprep<<<dim3(24,24,1), blk, 0, stream>>>(Wkp, WKP, 768);
  k_wprep<<<dim3(24,24,1), blk, 0, stream>>>(Wvp, WVP, 768);

  // LN -> XN stored in Vb, plus row stats
  k_ln<<<dim3(32768), blk, 0, stream>>>(text, images, ln_g, ln_b, Vb, muv, rsd);

  // Q, K projections read XN@Vb
  k_gemm<0><<<dim3(12,512), blk, 0, stream>>>(Vb, nullptr, nullptr, nullptr, nullptr,
      nullptr, nullptr, WQ_T, WQ_I, bsq, biq, Qb, tlen, ilen, 0);
  k_gemm<0><<<dim3(12,512), blk, 0, stream>>>(Vb, nullptr, nullptr, nullptr, nullptr,
      nullptr, nullptr, WK_T, WK_I, bsk, bik, Kb, tlen, ilen, 0);
  // V projection: LN on the fly from f32 inputs, writes V^T over Vb
  k_gemm<1><<<dim3(12,512), blk, 0, stream>>>(nullptr, text, images, muv, rsd,
      ln_g, ln_b, WV_T, WV_I, bsv, biv, Vb, tlen, ilen, 2);

  // attention stage 1: album written in-place over Qb (Q layout)
  k_attn1<<<dim3(16,128), blk, 0, stream>>>(Qb, Kb, Vb);

  // keys/vals projections read album@Qb; keys row-major over Kb, vals^T over Vb
  k_gemm<2><<<dim3(12,512), blk, 0, stream>>>(Qb, nullptr, nullptr, nullptr, nullptr,
      nullptr, nullptr, WKP, WKP, bkp, bkp, Kb, tlen, ilen, 1);
  k_gemm<2><<<dim3(12,512), blk, 0, stream>>>(Qb, nullptr, nullptr, nullptr, nullptr,
      nullptr, nullptr, WVP, WVP, bvp, bvp, Vb, tlen, ilen, 3);

  k_attn2<<<dim3(64), blk, 0, stream>>>(query, Kb, Vb, qlen, (float*)d_out);
}

// Round 5
// 581.968 us; speedup vs baseline: 2.8507x; 1.6187x over previous
//
#include <hip/hip_runtime.h>
#include <hip/hip_bf16.h>

typedef _Float16 h16;
typedef _Float16 h16x8 __attribute__((ext_vector_type(8)));
typedef _Float16 h16x4 __attribute__((ext_vector_type(4)));
typedef float    f32x4 __attribute__((ext_vector_type(4)));

#define MFMA(a,b,c) __builtin_amdgcn_mfma_f32_16x16x32_f16((a),(b),(c),0,0,0)

// H=2 B=64 LT=384 LI=128 L=512 D=768 K=V=384 DK=DV=768 LQ=24

__global__ __launch_bounds__(256) void k_diag(float* out, int n, float val) {
  int i = blockIdx.x * 256 + threadIdx.x;
  if (i < n) out[i] = val;
}

// ---------------- LayerNorm stats only (mu, rstd per row)
__global__ __launch_bounds__(256) void k_lnstat(
    const float* __restrict__ text, const float* __restrict__ images,
    float* __restrict__ muv, float* __restrict__ rsd)
{
  int row = blockIdx.x;
  int b = row >> 9, l = row & 511;
  const float* src = (l < 384) ? (text + ((size_t)b*384 + l)*768)
                               : (images + ((size_t)b*128 + (l-384))*768);
  int t = threadIdx.x;
  float x0 = src[t], x1 = src[t+256], x2 = src[t+512];
  __shared__ float red[8];
  float s = x0 + x1 + x2;
  #pragma unroll
  for (int m = 32; m; m >>= 1) s += __shfl_xor(s, m);
  int wid = t >> 6;
  if ((t & 63) == 0) red[wid] = s;
  __syncthreads();
  float mu = (red[0]+red[1]+red[2]+red[3]) * (1.0f/768.0f);
  float d0 = x0-mu, d1 = x1-mu, d2 = x2-mu;
  float v = d0*d0 + d1*d1 + d2*d2;
  #pragma unroll
  for (int m = 32; m; m >>= 1) v += __shfl_xor(v, m);
  if ((t & 63) == 0) red[4+wid] = v;
  __syncthreads();
  if (t == 0) {
    float var = (red[4]+red[5]+red[6]+red[7]) * (1.0f/768.0f);
    muv[row] = mu;
    rsd[row] = rsqrtf(var + 1e-5f);
  }
}

// ---------------- all weight transposes in ONE launch
// z 0..11: six (H=2,768,384) weights (w = z>>1, head = z&1) -> wb + w*WSZ
// z 12,13: Wkp, Wvp (768,768) -> wb + (6+z-12)*WSZ
__global__ __launch_bounds__(256) void k_wprep_all(
    const float* __restrict__ Wsq, const float* __restrict__ Wiq,
    const float* __restrict__ Wsk, const float* __restrict__ Wik,
    const float* __restrict__ Wsv, const float* __restrict__ Wiv,
    const float* __restrict__ Wkp, const float* __restrict__ Wvp,
    h16* __restrict__ wb)
{
  const size_t WSZ = 589824;
  int z = blockIdx.z;
  const float* src; h16* dst;
  int cols;
  if (z < 12) {
    if (blockIdx.x >= 12) return;
    int w = z >> 1, m = z & 1;
    const float* s6[6] = {Wsq, Wiq, Wsk, Wik, Wsv, Wiv};
    src = s6[w] + (size_t)m * 768 * 384;
    dst = wb + (size_t)w * WSZ + (size_t)m * 384 * 768;
    cols = 384;
  } else {
    src = (z == 12) ? Wkp : Wvp;
    dst = wb + (size_t)(6 + (z - 12)) * WSZ;
    cols = 768;
  }
  __shared__ float tile[32][33];
  int d0 = blockIdx.y * 32;
  int c0 = blockIdx.x * 32;
  int tx = threadIdx.x & 31, ty = threadIdx.x >> 5;
  #pragma unroll
  for (int i = 0; i < 32; i += 8)
    tile[ty+i][tx] = src[(size_t)(d0+ty+i)*cols + c0 + tx];
  __syncthreads();
  #pragma unroll
  for (int i = 0; i < 32; i += 8)
    dst[(size_t)(c0+ty+i)*768 + d0 + tx] = (h16)tile[tx][ty+i];
}

// ---------------- fused GEMM, 128x128 tile, 4 waves (each 64x64)
// AMODE 1: QKV projection. A = LN(text/images) on the fly. N = 2304
//   widx 0 -> Q (head-split layout), 1 -> K (same), 2 -> V^T
// AMODE 2: keys/vals projection. A = album@Qb (Q-layout). N = 1536
//   widx 0 -> keys row-major, 1 -> vals^T
// Fully-padded text M-tiles skip the K loop (outputs are zeros).
#define LDSKg 72
#define HOFF ((size_t)64*512*384)
template<int AMODE>
__global__ __launch_bounds__(256) void k_gemmf(
    const h16* __restrict__ Aalb,
    const float* __restrict__ Atext, const float* __restrict__ Aimg,
    const float* __restrict__ muv, const float* __restrict__ rsd,
    const float* __restrict__ gam, const float* __restrict__ bet,
    const h16* __restrict__ wb,
    const float* __restrict__ bsq, const float* __restrict__ biq,
    const float* __restrict__ bsk, const float* __restrict__ bik,
    const float* __restrict__ bsv, const float* __restrict__ biv,
    const float* __restrict__ bkp, const float* __restrict__ bvp,
    h16* __restrict__ O0, h16* __restrict__ O1, h16* __restrict__ O2,
    const int* __restrict__ tlen, const int* __restrict__ ilen)
{
  constexpr int NT = (AMODE == 1) ? 18 : 12;
  __shared__ __align__(16) h16 As[128*LDSKg];
  __shared__ __align__(16) h16 Bs[128*LDSKg];
  const size_t WSZ = 589824;
  int bid = blockIdx.x;
  int xcd = bid & 7, slot = bid >> 3;     // XCD-chunked: nt fastest per XCD
  int mt = xcd * 32 + slot / NT;
  int nt = slot % NT;
  int m0 = mt << 7;
  int b = m0 >> 9, l0 = m0 & 511;
  int TL = tlen[b], IL = ilen[b];
  bool skiptile = (l0 < 384) && (TL <= l0);   // image tile never fully padded
  int gc0 = nt << 7;
  int widx = gc0 / 768;
  int ncol0 = gc0 % 768;
  bool isimg = (l0 >= 384);

  const h16* BT;
  const float* bias;
  if constexpr (AMODE == 1) {
    BT = wb + ((size_t)(2*widx) + (isimg ? 1 : 0)) * WSZ;
    const float* bt6[6] = {bsq, biq, bsk, bik, bsv, biv};
    bias = bt6[2*widx + (isimg ? 1 : 0)];
  } else {
    BT = wb + (size_t)(6 + widx) * WSZ;
    bias = widx ? bvp : bkp;
  }

  int t = threadIdx.x;
  int lane = t & 63, wid = t >> 6;
  int wm = wid >> 1, wn = wid & 1;
  int lg = lane >> 4, li = lane & 15;
  int sr = t >> 3, sc8 = (t & 7) * 8;

  f32x4 acc[4][4] = {};

  if (!skiptile) {
    const float* af32[4];
    float amu[4], ars[4];
    const h16* aalb[4];
    const h16* brow[4];
    #pragma unroll
    for (int half = 0; half < 4; ++half) {
      int r = sr + half*32;
      int l = l0 + r;
      if constexpr (AMODE == 1) {
        af32[half] = (l < 384) ? (Atext + ((size_t)b*384 + l)*768)
                               : (Aimg  + ((size_t)b*128 + (l-384))*768);
        amu[half] = muv[m0 + r]; ars[half] = rsd[m0 + r];
      } else {
        aalb[half] = Aalb + ((size_t)b*512 + l)*384;
      }
      brow[half] = BT + (size_t)(ncol0 + r)*768;
    }
    for (int kt = 0; kt < 768; kt += 64) {
      int d = kt + sc8;
      f32x4 g0, g1, e0, e1;
      if constexpr (AMODE == 1) {
        g0 = *(const f32x4*)&gam[d]; g1 = *(const f32x4*)&gam[d+4];
        e0 = *(const f32x4*)&bet[d]; e1 = *(const f32x4*)&bet[d+4];
      }
      bool hd = (kt >= 384);
      #pragma unroll
      for (int half = 0; half < 4; ++half) {
        int r = sr + half*32;
        if constexpr (AMODE == 1) {
          f32x4 x0 = *(const f32x4*)&af32[half][d];
          f32x4 x1 = *(const f32x4*)&af32[half][d+4];
          float mu = amu[half], rs = ars[half];
          h16x8 o;
          #pragma unroll
          for (int j = 0; j < 4; ++j) o[j]   = (h16)((x0[j]-mu)*rs*g0[j] + e0[j]);
          #pragma unroll
          for (int j = 0; j < 4; ++j) o[4+j] = (h16)((x1[j]-mu)*rs*g1[j] + e1[j]);
          *(h16x8*)&As[r*LDSKg + sc8] = o;
        } else {
          const h16* p = aalb[half] + (hd ? (HOFF - 384 + (size_t)d) : (size_t)d);
          *(uint4*)&As[r*LDSKg + sc8] = *(const uint4*)p;
        }
        *(uint4*)&Bs[r*LDSKg + sc8] = *(const uint4*)&brow[half][d];
      }
      __syncthreads();
      #pragma unroll
      for (int ks = 0; ks < 2; ++ks) {
        int kc = ks*32 + lg*8;
        h16x8 af[4], bf[4];
        #pragma unroll
        for (int i = 0; i < 4; ++i) {
          af[i] = *(const h16x8*)&As[(wm*64 + i*16 + li)*LDSKg + kc];
          bf[i] = *(const h16x8*)&Bs[(wn*64 + i*16 + li)*LDSKg + kc];
        }
        #pragma unroll
        for (int i = 0; i < 4; ++i)
          #pragma unroll
          for (int j = 0; j < 4; ++j)
            acc[i][j] = MFMA(af[i], bf[j], acc[i][j]);
      }
      __syncthreads();
    }
  }

  // epilogue: bias, pad-zero, route
  bool vroute = (AMODE == 1) ? (widx == 2) : (widx == 1);
  h16* dsc = (AMODE == 1) ? (widx == 0 ? O0 : O1) : O0;  // scalar routes
  h16* dsv = (AMODE == 1) ? O2 : O1;                     // transposed routes
  #pragma unroll
  for (int i = 0; i < 4; ++i)
    #pragma unroll
    for (int j = 0; j < 4; ++j) {
      int colL = wn*64 + j*16 + li;
      int col_in = ncol0 + colL;
      float bv = bias[col_in];
      int lb = l0 + wm*64 + i*16 + lg*4;
      int hh = (col_in >= 384) ? 1 : 0;
      int kk = col_in - hh*384;
      if (vroute) {
        h16x4 pk;
        #pragma unroll
        for (int r = 0; r < 4; ++r) {
          int l = lb + r;
          float v = acc[i][j][r] + bv;
          bool pad = (l < 384) ? (l >= TL) : ((l-384) >= IL);
          pk[r] = (h16)(pad ? 0.0f : v);
        }
        size_t oi;
        if constexpr (AMODE == 1)
          oi = (((size_t)(hh*64 + b))*384 + kk)*512 + lb;
        else
          oi = ((size_t)b*768 + col_in)*512 + lb;
        *(h16x4*)&dsv[oi] = pk;
      } else {
        #pragma unroll
        for (int r = 0; r < 4; ++r) {
          int l = lb + r;
          float v = acc[i][j][r] + bv;
          bool pad = (l < 384) ? (l >= TL) : ((l-384) >= IL);
          if (pad) v = 0.0f;
          size_t oi;
          if constexpr (AMODE == 1)
            oi = (((size_t)(hh*64 + b))*512 + l)*384 + kk;
          else
            oi = ((size_t)b*512 + l)*768 + col_in;
          dsc[oi] = (h16)v;
        }
      }
    }
}

// ---------------- attention stage 1: per (h,b), 32 q-rows per block
// V TRANSPOSED; skips: fully-padded q-tiles, fully-padded key groups.
__global__ __launch_bounds__(256) void k_attn1(
    h16* Qb, const h16* __restrict__ Kb, const h16* __restrict__ Vt,
    const int* __restrict__ tlen, const int* __restrict__ ilen)
{
  __shared__ __align__(16) float S[32*516];
  __shared__ float rowscale[32];
  int hb = blockIdx.y;
  int q0 = blockIdx.x * 32;
  int b = hb & 63;
  int TL = tlen[b], IL = ilen[b];
  h16* Qp = Qb + (size_t)hb * 512 * 384;
  const h16* Kp = Kb + (size_t)hb * 512 * 384;
  const h16* Vp = Vt + (size_t)hb * 384 * 512;
  int t = threadIdx.x, lane = t & 63, w = t >> 6;
  int lg = lane >> 4, li = lane & 15;

  bool qskip = (q0 < 384) ? (TL <= q0) : (IL <= q0 - 384);
  if (qskip) {
    h16x8 z = {};
    for (int c = t; c < 1536; c += 256) {
      int row = c / 48, v8 = (c % 48) * 8;
      *(h16x8*)&Qp[(size_t)(q0+row)*384 + v8] = z;
    }
    return;
  }

  // Q fragments in registers: 2 m-frags x 12 k-steps
  h16x8 aq[2][12];
  #pragma unroll
  for (int m = 0; m < 2; ++m)
    #pragma unroll
    for (int ks = 0; ks < 12; ++ks)
      aq[m][ks] = *(const h16x8*)&Qp[(size_t)(q0 + m*16 + li)*384 + ks*32 + lg*8];

  // scores: wave w owns keys [w*128, w*128+128)
  int kbase = w * 128;
  for (int nf = 0; nf < 8; ++nf) {
    int kcol = kbase + nf*16;
    bool kskip = (kcol < 384) ? (TL <= kcol) : (IL <= kcol - 384);
    if (kskip) {
      #pragma unroll
      for (int r = 0; r < 4; ++r) {
        int c = kcol + li;
        S[(lg*4 + r)*516 + c] = -__builtin_inff();
        S[(16 + lg*4 + r)*516 + c] = -__builtin_inff();
      }
      continue;
    }
    f32x4 acc0 = {0,0,0,0}, acc1 = {0,0,0,0};
    #pragma unroll
    for (int ks = 0; ks < 12; ++ks) {
      h16x8 bk = *(const h16x8*)&Kp[(size_t)(kcol + li)*384 + ks*32 + lg*8];
      acc0 = MFMA(aq[0][ks], bk, acc0);
      acc1 = MFMA(aq[1][ks], bk, acc1);
    }
    #pragma unroll
    for (int r = 0; r < 4; ++r) {
      int c = kcol + li;
      int row0 = lg*4 + r;
      float v0 = acc0[r];
      if (v0 == 0.0f || (q0 + row0) == c) v0 = -__builtin_inff();
      S[row0*516 + c] = v0;
      int row1 = 16 + lg*4 + r;
      float v1 = acc1[r];
      if (v1 == 0.0f || (q0 + row1) == c) v1 = -__builtin_inff();
      S[row1*516 + c] = v1;
    }
  }
  __syncthreads();
  // masked softmax; P stored UNNORMALIZED (scale at epilogue)
  {
    int row = t >> 3, ci = t & 7;
    float mx = -3e38f;
    for (int j = 0; j < 64; ++j) mx = fmaxf(mx, S[row*516 + ci + j*8]);
    mx = fmaxf(mx, __shfl_xor(mx, 1));
    mx = fmaxf(mx, __shfl_xor(mx, 2));
    mx = fmaxf(mx, __shfl_xor(mx, 4));
    float sum = 0.0f;
    for (int j = 0; j < 64; ++j) {
      float e = __expf(S[row*516 + ci + j*8] - mx);
      S[row*516 + ci + j*8] = e;
      sum += e;
    }
    sum += __shfl_xor(sum, 1);
    sum += __shfl_xor(sum, 2);
    sum += __shfl_xor(sum, 4);
    if (ci == 0) rowscale[row] = 1.0f / (sum > 0.0f ? sum : 1.0f);
  }
  __syncthreads();
  // PV: wave w owns v-cols [w*96, w*96+96); skip fully-padded 32-key groups
  f32x4 oacc[2][6] = {};
  int v0w = w * 96;
  for (int kt = 0; kt < 16; ++kt) {
    int k0 = kt * 32;
    bool vskip = (k0 < 384) ? (TL <= k0) : (IL <= k0 - 384);
    if (vskip) continue;
    h16x8 bv[6];
    #pragma unroll
    for (int n = 0; n < 6; ++n)
      bv[n] = *(const h16x8*)&Vp[(size_t)(v0w + n*16 + li)*512 + k0 + lg*8];
    #pragma unroll
    for (int m = 0; m < 2; ++m) {
      int row = m*16 + li;
      f32x4 p0 = *(const f32x4*)&S[row*516 + k0 + lg*8];
      f32x4 p1 = *(const f32x4*)&S[row*516 + k0 + lg*8 + 4];
      h16x8 pa;
      pa[0]=(h16)p0[0]; pa[1]=(h16)p0[1]; pa[2]=(h16)p0[2]; pa[3]=(h16)p0[3];
      pa[4]=(h16)p1[0]; pa[5]=(h16)p1[1]; pa[6]=(h16)p1[2]; pa[7]=(h16)p1[3];
      #pragma unroll
      for (int n = 0; n < 6; ++n)
        oacc[m][n] = MFMA(pa, bv[n], oacc[m][n]);
    }
  }
  #pragma unroll
  for (int m = 0; m < 2; ++m)
    #pragma unroll
    for (int n = 0; n < 6; ++n)
      #pragma unroll
      for (int r = 0; r < 4; ++r) {
        int row = m*16 + lg*4 + r;
        int col = v0w + n*16 + li;
        Qp[(size_t)(q0 + row)*384 + col] = (h16)(oacc[m][n][r] * rowscale[row]);
      }
}

// ---------------- attention stage 2 + mean: one block per b (vals TRANSPOSED)
__global__ __launch_bounds__(256) void k_attn2(
    const float* __restrict__ query, const h16* __restrict__ keys,
    const h16* __restrict__ valsT, const int* __restrict__ qlen,
    const int* __restrict__ tlen, const int* __restrict__ ilen,
    float* __restrict__ out)
{
  __shared__ __align__(16) float S[32*516];
  __shared__ __align__(16) h16 UB[32*776];
  __shared__ float rowscale[32];
  int b = blockIdx.x;
  const float* Qp = query + (size_t)b*24*768;
  const h16* Kp = keys + (size_t)b*512*768;
  const h16* Vp = valsT + (size_t)b*768*512;
  int t = threadIdx.x, lane = t & 63, w = t >> 6;
  int lg = lane >> 4, li = lane & 15;
  int ql = qlen[b];
  int TL = tlen[b], IL = ilen[b];
  for (int c = t; c < 3072; c += 256) {
    int row = c / 96, vv = (c % 96) * 8;
    h16x8 a = {};
    if (row < 24 && row < ql) {
      f32x4 f0 = *(const f32x4*)&Qp[(size_t)row*768 + vv];
      f32x4 f1 = *(const f32x4*)&Qp[(size_t)row*768 + vv + 4];
      a[0]=(h16)f0[0]; a[1]=(h16)f0[1]; a[2]=(h16)f0[2]; a[3]=(h16)f0[3];
      a[4]=(h16)f1[0]; a[5]=(h16)f1[1]; a[6]=(h16)f1[2]; a[7]=(h16)f1[3];
    }
    *(h16x8*)&UB[row*776 + vv] = a;
  }
  __syncthreads();
  int kbase = w * 128;
  for (int nf = 0; nf < 8; ++nf) {
    int kcol = kbase + nf*16;
    bool kskip = (kcol < 384) ? (TL <= kcol) : (IL <= kcol - 384);
    if (kskip) {
      #pragma unroll
      for (int r = 0; r < 4; ++r) {
        int c = kcol + li;
        S[(lg*4 + r)*516 + c] = -__builtin_inff();
        S[(16 + lg*4 + r)*516 + c] = -__builtin_inff();
      }
      continue;
    }
    f32x4 acc0 = {0,0,0,0}, acc1 = {0,0,0,0};
    #pragma unroll
    for (int ks = 0; ks < 24; ++ks) {
      h16x8 a0 = *(const h16x8*)&UB[(li)*776      + ks*32 + lg*8];
      h16x8 a1 = *(const h16x8*)&UB[(16 + li)*776 + ks*32 + lg*8];
      h16x8 bk = *(const h16x8*)&Kp[(size_t)(kcol + li)*768 + ks*32 + lg*8];
      acc0 = MFMA(a0, bk, acc0);
      acc1 = MFMA(a1, bk, acc1);
    }
    #pragma unroll
    for (int r = 0; r < 4; ++r) {
      int c = kcol + li;
      float v0 = acc0[r];
      if (v0 == 0.0f) v0 = -__builtin_inff();
      S[(lg*4 + r)*516 + c] = v0;
      float v1 = acc1[r];
      if (v1 == 0.0f) v1 = -__builtin_inff();
      S[(16 + lg*4 + r)*516 + c] = v1;
    }
  }
  __syncthreads();
  {
    int row = t >> 3, ci = t & 7;
    float mx = -3e38f;
    for (int j = 0; j < 64; ++j) mx = fmaxf(mx, S[row*516 + ci + j*8]);
    mx = fmaxf(mx, __shfl_xor(mx, 1));
    mx = fmaxf(mx, __shfl_xor(mx, 2));
    mx = fmaxf(mx, __shfl_xor(mx, 4));
    float sum = 0.0f;
    for (int j = 0; j < 64; ++j) {
      float e = __expf(S[row*516 + ci + j*8] - mx);
      S[row*516 + ci + j*8] = e;
      sum += e;
    }
    sum += __shfl_xor(sum, 1);
    sum += __shfl_xor(sum, 2);
    sum += __shfl_xor(sum, 4);
    if (ci == 0) rowscale[row] = 1.0f / (sum > 0.0f ? sum : 1.0f);
  }
  __syncthreads();
  for (int vh = 0; vh < 2; ++vh) {
    f32x4 oacc[2][6] = {};
    for (int kt = 0; kt < 16; ++kt) {
      int k0 = kt * 32;
      bool vskip = (k0 < 384) ? (TL <= k0) : (IL <= k0 - 384);
      if (vskip) continue;
      h16x8 bv[6];
      #pragma unroll
      for (int n = 0; n < 6; ++n)
        bv[n] = *(const h16x8*)&Vp[(size_t)(vh*384 + w*96 + n*16 + li)*512 + k0 + lg*8];
      #pragma unroll
      for (int m = 0; m < 2; ++m) {
        int row = m*16 + li;
        f32x4 p0 = *(const f32x4*)&S[row*516 + k0 + lg*8];
        f32x4 p1 = *(const f32x4*)&S[row*516 + k0 + lg*8 + 4];
        h16x8 pa;
        pa[0]=(h16)p0[0]; pa[1]=(h16)p0[1]; pa[2]=(h16)p0[2]; pa[3]=(h16)p0[3];
        pa[4]=(h16)p1[0]; pa[5]=(h16)p1[1]; pa[6]=(h16)p1[2]; pa[7]=(h16)p1[3];
        #pragma unroll
        for (int n = 0; n < 6; ++n)
          oacc[m][n] = MFMA(pa, bv[n], oacc[m][n]);
      }
    }
    #pragma unroll
    for (int n = 0; n < 6; ++n) {
      float cs = 0.0f;
      #pragma unroll
      for (int m = 0; m < 2; ++m)
        #pragma unroll
        for (int r = 0; r < 4; ++r)
          cs += oacc[m][n][r] * rowscale[m*16 + lg*4 + r];
      cs += __shfl_xor(cs, 16);
      cs += __shfl_xor(cs, 32);
      if (lg == 0) out[(size_t)b*768 + vh*384 + w*96 + n*16 + li] = cs * (1.0f/24.0f);
    }
  }
}

extern "C" void kernel_launch(void* const* d_in, const int* in_sizes, int n_in,
                              void* d_out, int out_size, void* d_ws, size_t ws_size,
                              hipStream_t stream)
{
  (void)in_sizes; (void)n_in;
  const float* text  = (const float*)d_in[0];
  const float* images= (const float*)d_in[1];
  const float* query = (const float*)d_in[2];
  const float* ln_g  = (const float*)d_in[3];
  const float* ln_b  = (const float*)d_in[4];
  const float* Wsq = (const float*)d_in[5];
  const float* bsq = (const float*)d_in[6];
  const float* Wiq = (const float*)d_in[7];
  const float* biq = (const float*)d_in[8];
  const float* Wsk = (const float*)d_in[9];
  const float* bsk = (const float*)d_in[10];
  const float* Wik = (const float*)d_in[11];
  const float* bik = (const float*)d_in[12];
  const float* Wsv = (const float*)d_in[13];
  const float* bsv = (const float*)d_in[14];
  const float* Wiv = (const float*)d_in[15];
  const float* biv = (const float*)d_in[16];
  const float* Wkp = (const float*)d_in[17];
  const float* bkp = (const float*)d_in[18];
  const float* Wvp = (const float*)d_in[19];
  const float* bvp = (const float*)d_in[20];
  const int* tlen = (const int*)d_in[21];
  const int* ilen = (const int*)d_in[22];
  const int* qlen = (const int*)d_in[23];

  // workspace: [0,256KB) mu/rstd; [256KB,+9.4MB) 8 fp16 weights;
  // 3 x 50.33MB: Qb (->album), Kb (->keys), Vb (V^T -> vals^T)
  const size_t NEED = 160694272;
  if (ws_size < NEED) {
    k_diag<<<dim3((out_size+255)/256), dim3(256), 0, stream>>>((float*)d_out, out_size, 1.0e6f);
    return;
  }
  float* muv = (float*)d_ws;
  float* rsd = muv + 32768;
  h16* wb = (h16*)((char*)d_ws + 262144);
  const size_t WSZ = 589824;
  const size_t TSZ = (size_t)32768*768;
  h16* Qb = wb + 8*WSZ;
  h16* Kb = Qb + TSZ;
  h16* Vb = Kb + TSZ;

  dim3 blk(256);
  k_wprep_all<<<dim3(24,24,14), blk, 0, stream>>>(Wsq, Wiq, Wsk, Wik, Wsv, Wiv, Wkp, Wvp, wb);
  k_lnstat<<<dim3(32768), blk, 0, stream>>>(text, images, muv, rsd);

  // fused QKV projection (LN on the fly): Qb, Kb, Vb^T
  k_gemmf<1><<<dim3(4608), blk, 0, stream>>>(nullptr, text, images, muv, rsd,
      ln_g, ln_b, wb, bsq, biq, bsk, bik, bsv, biv, bkp, bvp,
      Qb, Kb, Vb, tlen, ilen);

  // attention stage 1: album written in-place over Qb (Q layout)
  k_attn1<<<dim3(16,128), blk, 0, stream>>>(Qb, Kb, Vb, tlen, ilen);

  // fused keys/vals projection: keys@Kb (row-major), vals^T@Vb
  k_gemmf<2><<<dim3(3072), blk, 0, stream>>>(Qb, nullptr, nullptr, nullptr, nullptr,
      nullptr, nullptr, wb, bsq, biq, bsk, bik, bsv, biv, bkp, bvp,
      Kb, Vb, nullptr, tlen, ilen);

  k_attn2<<<dim3(64), blk, 0, stream>>>(query, Kb, Vb, qlen, tlen, ilen, (float*)d_out);
}

// Round 6
// 570.547 us; speedup vs baseline: 2.9078x; 1.0200x over previous
//
#include <hip/hip_runtime.h>
#include <hip/hip_bf16.h>

typedef _Float16 h16;
typedef _Float16 h16x8 __attribute__((ext_vector_type(8)));
typedef _Float16 h16x4 __attribute__((ext_vector_type(4)));
typedef float    f32x4 __attribute__((ext_vector_type(4)));

#define MFMA(a,b,c) __builtin_amdgcn_mfma_f32_16x16x32_f16((a),(b),(c),0,0,0)

// H=2 B=64 LT=384 LI=128 L=512 D=768 K=V=384 DK=DV=768 LQ=24

typedef __attribute__((address_space(1))) const void gas_void;
typedef __attribute__((address_space(3))) void las_void;
__device__ __forceinline__ void gld16(void* l, const void* g) {
  __builtin_amdgcn_global_load_lds((gas_void*)g, (las_void*)l, 16, 0, 0);
}

__global__ __launch_bounds__(256) void k_diag(float* out, int n, float val) {
  int i = blockIdx.x * 256 + threadIdx.x;
  if (i < n) out[i] = val;
}

// ---------------- LayerNorm -> fp16 XN[b*512+l][768] (no stats needed)
__global__ __launch_bounds__(256) void k_ln(
    const float* __restrict__ text, const float* __restrict__ images,
    const float* __restrict__ g, const float* __restrict__ be,
    h16* __restrict__ xn)
{
  int row = blockIdx.x;
  int b = row >> 9, l = row & 511;
  const float* src = (l < 384) ? (text + ((size_t)b*384 + l)*768)
                               : (images + ((size_t)b*128 + (l-384))*768);
  int t = threadIdx.x;
  float x0 = src[t], x1 = src[t+256], x2 = src[t+512];
  __shared__ float red[8];
  float s = x0 + x1 + x2;
  #pragma unroll
  for (int m = 32; m; m >>= 1) s += __shfl_xor(s, m);
  int wid = t >> 6;
  if ((t & 63) == 0) red[wid] = s;
  __syncthreads();
  float mu = (red[0]+red[1]+red[2]+red[3]) * (1.0f/768.0f);
  float d0 = x0-mu, d1 = x1-mu, d2 = x2-mu;
  float v = d0*d0 + d1*d1 + d2*d2;
  #pragma unroll
  for (int m = 32; m; m >>= 1) v += __shfl_xor(v, m);
  if ((t & 63) == 0) red[4+wid] = v;
  __syncthreads();
  float var = (red[4]+red[5]+red[6]+red[7]) * (1.0f/768.0f);
  float rstd = rsqrtf(var + 1e-5f);
  h16* dst = xn + (size_t)row * 768;
  dst[t]     = (h16)(d0*rstd*g[t]     + be[t]);
  dst[t+256] = (h16)(d1*rstd*g[t+256] + be[t+256]);
  dst[t+512] = (h16)(d2*rstd*g[t+512] + be[t+512]);
}

// ---------------- LayerNorm stats only (fallback path)
__global__ __launch_bounds__(256) void k_lnstat(
    const float* __restrict__ text, const float* __restrict__ images,
    float* __restrict__ muv, float* __restrict__ rsd)
{
  int row = blockIdx.x;
  int b = row >> 9, l = row & 511;
  const float* src = (l < 384) ? (text + ((size_t)b*384 + l)*768)
                               : (images + ((size_t)b*128 + (l-384))*768);
  int t = threadIdx.x;
  float x0 = src[t], x1 = src[t+256], x2 = src[t+512];
  __shared__ float red[8];
  float s = x0 + x1 + x2;
  #pragma unroll
  for (int m = 32; m; m >>= 1) s += __shfl_xor(s, m);
  int wid = t >> 6;
  if ((t & 63) == 0) red[wid] = s;
  __syncthreads();
  float mu = (red[0]+red[1]+red[2]+red[3]) * (1.0f/768.0f);
  float d0 = x0-mu, d1 = x1-mu, d2 = x2-mu;
  float v = d0*d0 + d1*d1 + d2*d2;
  #pragma unroll
  for (int m = 32; m; m >>= 1) v += __shfl_xor(v, m);
  if ((t & 63) == 0) red[4+wid] = v;
  __syncthreads();
  if (t == 0) {
    float var = (red[4]+red[5]+red[6]+red[7]) * (1.0f/768.0f);
    muv[row] = mu;
    rsd[row] = rsqrtf(var + 1e-5f);
  }
}

// ---------------- all weight transposes in ONE launch
__global__ __launch_bounds__(256) void k_wprep_all(
    const float* __restrict__ Wsq, const float* __restrict__ Wiq,
    const float* __restrict__ Wsk, const float* __restrict__ Wik,
    const float* __restrict__ Wsv, const float* __restrict__ Wiv,
    const float* __restrict__ Wkp, const float* __restrict__ Wvp,
    h16* __restrict__ wb)
{
  const size_t WSZ = 589824;
  int z = blockIdx.z;
  const float* src; h16* dst;
  int cols;
  if (z < 12) {
    if (blockIdx.x >= 12) return;
    int w = z >> 1, m = z & 1;
    const float* s6[6] = {Wsq, Wiq, Wsk, Wik, Wsv, Wiv};
    src = s6[w] + (size_t)m * 768 * 384;
    dst = wb + (size_t)w * WSZ + (size_t)m * 384 * 768;
    cols = 384;
  } else {
    src = (z == 12) ? Wkp : Wvp;
    dst = wb + (size_t)(6 + (z - 12)) * WSZ;
    cols = 768;
  }
  __shared__ float tile[32][33];
  int d0 = blockIdx.y * 32;
  int c0 = blockIdx.x * 32;
  int tx = threadIdx.x & 31, ty = threadIdx.x >> 5;
  #pragma unroll
  for (int i = 0; i < 32; i += 8)
    tile[ty+i][tx] = src[(size_t)(d0+ty+i)*cols + c0 + tx];
  __syncthreads();
  #pragma unroll
  for (int i = 0; i < 32; i += 8)
    dst[(size_t)(c0+ty+i)*768 + d0 + tx] = (h16)tile[tx][ty+i];
}

#define HOFF ((size_t)64*512*384)

// ---------------- NEW GEMM: global_load_lds staging, linear LDS [128][64]
// AMODE 0: QKV. A = XN fp16 [row][768]. N = 2304 (widx 0 Q, 1 K, 2 V^T)
// AMODE 2: keys/vals. A = album@Qb (Q-layout head-split). N = 1536
template<int AMODE>
__global__ __launch_bounds__(256) void k_gemmf2(
    const h16* __restrict__ Asrc, const h16* __restrict__ wb,
    const float* __restrict__ bsq, const float* __restrict__ biq,
    const float* __restrict__ bsk, const float* __restrict__ bik,
    const float* __restrict__ bsv, const float* __restrict__ biv,
    const float* __restrict__ bkp, const float* __restrict__ bvp,
    h16* __restrict__ O0, h16* __restrict__ O1, h16* __restrict__ O2,
    const int* __restrict__ tlen, const int* __restrict__ ilen)
{
  constexpr int NT = (AMODE == 0) ? 18 : 12;
  __shared__ __align__(16) h16 As[128*64];
  __shared__ __align__(16) h16 Bs[128*64];
  const size_t WSZ = 589824;
  int bid = blockIdx.x;
  int xcd = bid & 7, slot = bid >> 3;     // XCD-chunked: nt fastest per XCD
  int mt = xcd * 32 + slot / NT;
  int nt = slot % NT;
  int m0 = mt << 7;
  int b = m0 >> 9, l0 = m0 & 511;
  int TL = tlen[b], IL = ilen[b];
  bool skiptile = (l0 < 384) && (TL <= l0);
  int gc0 = nt << 7;
  int widx = gc0 / 768;
  int ncol0 = gc0 % 768;
  bool isimg = (l0 >= 384);

  const h16* BT;
  const float* bias;
  if constexpr (AMODE == 0) {
    BT = wb + ((size_t)(2*widx) + (isimg ? 1 : 0)) * WSZ;
    const float* bt6[6] = {bsq, biq, bsk, bik, bsv, biv};
    bias = bt6[2*widx + (isimg ? 1 : 0)];
  } else {
    BT = wb + (size_t)(6 + widx) * WSZ;
    bias = widx ? bvp : bkp;
  }

  int t = threadIdx.x;
  int lane = t & 63, wid = t >> 6;
  int wm = wid >> 1, wn = wid & 1;
  int lg = lane >> 4, li = lane & 15;

  f32x4 acc[4][4] = {};

  if (!skiptile) {
    // staging descriptors: thread t covers chunk ci = h*256+t (row=ci>>3, c=ci&7)
    const h16* pA[4]; const h16* pB[4];
    h16* ldsA[4]; h16* ldsB[4];
    #pragma unroll
    for (int h = 0; h < 4; ++h) {
      int ci = h*256 + t;
      int row = ci >> 3, c = ci & 7;
      if constexpr (AMODE == 0) {
        pA[h] = Asrc + (size_t)(m0 + row)*768 + c*8;
      } else {
        pA[h] = Asrc + ((size_t)b*512 + l0 + row)*384 + c*8;
      }
      pB[h] = BT + (size_t)(ncol0 + row)*768 + c*8;
      ldsA[h] = &As[(size_t)(h*256 + wid*64)*8];   // wave-uniform dest base
      ldsB[h] = &Bs[(size_t)(h*256 + wid*64)*8];
    }
    for (int kt = 0; kt < 768; kt += 64) {
      size_t aoff = kt;
      if constexpr (AMODE == 2) aoff = (size_t)kt + ((kt >= 384) ? (HOFF - 384) : 0);
      #pragma unroll
      for (int h = 0; h < 4; ++h) {
        gld16(ldsA[h], pA[h] + aoff);
        gld16(ldsB[h], pB[h] + kt);
      }
      __syncthreads();
      #pragma unroll
      for (int ks = 0; ks < 2; ++ks) {
        int kc = ks*32 + lg*8;
        h16x8 af[4], bf[4];
        #pragma unroll
        for (int i = 0; i < 4; ++i) {
          af[i] = *(const h16x8*)&As[(size_t)(wm*64 + i*16 + li)*64 + kc];
          bf[i] = *(const h16x8*)&Bs[(size_t)(wn*64 + i*16 + li)*64 + kc];
        }
        #pragma unroll
        for (int i = 0; i < 4; ++i)
          #pragma unroll
          for (int j = 0; j < 4; ++j)
            acc[i][j] = MFMA(af[i], bf[j], acc[i][j]);
      }
      __syncthreads();
    }
  }

  // epilogue: bias, pad-zero, route
  bool vroute = (AMODE == 0) ? (widx == 2) : (widx == 1);
  h16* dsc = (AMODE == 0) ? (widx == 0 ? O0 : O1) : O0;
  h16* dsv = (AMODE == 0) ? O2 : O1;
  #pragma unroll
  for (int i = 0; i < 4; ++i)
    #pragma unroll
    for (int j = 0; j < 4; ++j) {
      int colL = wn*64 + j*16 + li;
      int col_in = ncol0 + colL;
      float bv = bias[col_in];
      int lb = l0 + wm*64 + i*16 + lg*4;
      int hh = (col_in >= 384) ? 1 : 0;
      int kk = col_in - hh*384;
      if (vroute) {
        h16x4 pk;
        #pragma unroll
        for (int r = 0; r < 4; ++r) {
          int l = lb + r;
          float v = acc[i][j][r] + bv;
          bool pad = (l < 384) ? (l >= TL) : ((l-384) >= IL);
          pk[r] = (h16)(pad ? 0.0f : v);
        }
        size_t oi;
        if constexpr (AMODE == 0)
          oi = (((size_t)(hh*64 + b))*384 + kk)*512 + lb;
        else
          oi = ((size_t)b*768 + col_in)*512 + lb;
        *(h16x4*)&dsv[oi] = pk;
      } else {
        #pragma unroll
        for (int r = 0; r < 4; ++r) {
          int l = lb + r;
          float v = acc[i][j][r] + bv;
          bool pad = (l < 384) ? (l >= TL) : ((l-384) >= IL);
          if (pad) v = 0.0f;
          size_t oi;
          if constexpr (AMODE == 0)
            oi = (((size_t)(hh*64 + b))*512 + l)*384 + kk;
          else
            oi = ((size_t)b*512 + l)*768 + col_in;
          dsc[oi] = (h16)v;
        }
      }
    }
}

// ---------------- FALLBACK GEMM (round-5 AMODE1: LN on the fly), used if ws too small
#define LDSKg 72
__global__ __launch_bounds__(256) void k_gemmf_fb(
    const float* __restrict__ Atext, const float* __restrict__ Aimg,
    const float* __restrict__ muv, const float* __restrict__ rsd,
    const float* __restrict__ gam, const float* __restrict__ bet,
    const h16* __restrict__ wb,
    const float* __restrict__ bsq, const float* __restrict__ biq,
    const float* __restrict__ bsk, const float* __restrict__ bik,
    const float* __restrict__ bsv, const float* __restrict__ biv,
    h16* __restrict__ O0, h16* __restrict__ O1, h16* __restrict__ O2,
    const int* __restrict__ tlen, const int* __restrict__ ilen)
{
  constexpr int NT = 18;
  __shared__ __align__(16) h16 As[128*LDSKg];
  __shared__ __align__(16) h16 Bs[128*LDSKg];
  const size_t WSZ = 589824;
  int bid = blockIdx.x;
  int xcd = bid & 7, slot = bid >> 3;
  int mt = xcd * 32 + slot / NT;
  int nt = slot % NT;
  int m0 = mt << 7;
  int b = m0 >> 9, l0 = m0 & 511;
  int TL = tlen[b], IL = ilen[b];
  bool skiptile = (l0 < 384) && (TL <= l0);
  int gc0 = nt << 7;
  int widx = gc0 / 768;
  int ncol0 = gc0 % 768;
  bool isimg = (l0 >= 384);
  const h16* BT = wb + ((size_t)(2*widx) + (isimg ? 1 : 0)) * WSZ;
  const float* bt6[6] = {bsq, biq, bsk, bik, bsv, biv};
  const float* bias = bt6[2*widx + (isimg ? 1 : 0)];

  int t = threadIdx.x;
  int lane = t & 63, wid = t >> 6;
  int wm = wid >> 1, wn = wid & 1;
  int lg = lane >> 4, li = lane & 15;
  int sr = t >> 3, sc8 = (t & 7) * 8;
  f32x4 acc[4][4] = {};
  if (!skiptile) {
    const float* af32[4];
    float amu[4], ars[4];
    const h16* brow[4];
    #pragma unroll
    for (int half = 0; half < 4; ++half) {
      int r = sr + half*32;
      int l = l0 + r;
      af32[half] = (l < 384) ? (Atext + ((size_t)b*384 + l)*768)
                             : (Aimg  + ((size_t)b*128 + (l-384))*768);
      amu[half] = muv[m0 + r]; ars[half] = rsd[m0 + r];
      brow[half] = BT + (size_t)(ncol0 + r)*768;
    }
    for (int kt = 0; kt < 768; kt += 64) {
      int d = kt + sc8;
      f32x4 g0 = *(const f32x4*)&gam[d], g1 = *(const f32x4*)&gam[d+4];
      f32x4 e0 = *(const f32x4*)&bet[d], e1 = *(const f32x4*)&bet[d+4];
      #pragma unroll
      for (int half = 0; half < 4; ++half) {
        int r = sr + half*32;
        f32x4 x0 = *(const f32x4*)&af32[half][d];
        f32x4 x1 = *(const f32x4*)&af32[half][d+4];
        float mu = amu[half], rs = ars[half];
        h16x8 o;
        #pragma unroll
        for (int j = 0; j < 4; ++j) o[j]   = (h16)((x0[j]-mu)*rs*g0[j] + e0[j]);
        #pragma unroll
        for (int j = 0; j < 4; ++j) o[4+j] = (h16)((x1[j]-mu)*rs*g1[j] + e1[j]);
        *(h16x8*)&As[r*LDSKg + sc8] = o;
        *(uint4*)&Bs[r*LDSKg + sc8] = *(const uint4*)&brow[half][d];
      }
      __syncthreads();
      #pragma unroll
      for (int ks = 0; ks < 2; ++ks) {
        int kc = ks*32 + lg*8;
        h16x8 af[4], bf[4];
        #pragma unroll
        for (int i = 0; i < 4; ++i) {
          af[i] = *(const h16x8*)&As[(wm*64 + i*16 + li)*LDSKg + kc];
          bf[i] = *(const h16x8*)&Bs[(wn*64 + i*16 + li)*LDSKg + kc];
        }
        #pragma unroll
        for (int i = 0; i < 4; ++i)
          #pragma unroll
          for (int j = 0; j < 4; ++j)
            acc[i][j] = MFMA(af[i], bf[j], acc[i][j]);
      }
      __syncthreads();
    }
  }
  bool vroute = (widx == 2);
  h16* dsc = (widx == 0 ? O0 : O1);
  #pragma unroll
  for (int i = 0; i < 4; ++i)
    #pragma unroll
    for (int j = 0; j < 4; ++j) {
      int colL = wn*64 + j*16 + li;
      int col_in = ncol0 + colL;
      float bv = bias[col_in];
      int lb = l0 + wm*64 + i*16 + lg*4;
      int hh = (col_in >= 384) ? 1 : 0;
      int kk = col_in - hh*384;
      if (vroute) {
        h16x4 pk;
        #pragma unroll
        for (int r = 0; r < 4; ++r) {
          int l = lb + r;
          float v = acc[i][j][r] + bv;
          bool pad = (l < 384) ? (l >= TL) : ((l-384) >= IL);
          pk[r] = (h16)(pad ? 0.0f : v);
        }
        size_t oi = (((size_t)(hh*64 + b))*384 + kk)*512 + lb;
        *(h16x4*)&O2[oi] = pk;
      } else {
        #pragma unroll
        for (int r = 0; r < 4; ++r) {
          int l = lb + r;
          float v = acc[i][j][r] + bv;
          bool pad = (l < 384) ? (l >= TL) : ((l-384) >= IL);
          if (pad) v = 0.0f;
          size_t oi = (((size_t)(hh*64 + b))*512 + l)*384 + kk;
          dsc[oi] = (h16)v;
        }
      }
    }
}

// ---------------- attention stage 1 (branch-free padding skips)
__global__ __launch_bounds__(256) void k_attn1(
    h16* Qb, const h16* __restrict__ Kb, const h16* __restrict__ Vt,
    const int* __restrict__ tlen, const int* __restrict__ ilen)
{
  __shared__ __align__(16) float S[32*516];
  __shared__ float rowscale[32];
  int hb = blockIdx.y;
  int q0 = blockIdx.x * 32;
  int b = hb & 63;
  int TL = tlen[b], IL = ilen[b];
  h16* Qp = Qb + (size_t)hb * 512 * 384;
  const h16* Kp = Kb + (size_t)hb * 512 * 384;
  const h16* Vp = Vt + (size_t)hb * 384 * 512;
  int t = threadIdx.x, lane = t & 63, w = t >> 6;
  int lg = lane >> 4, li = lane & 15;

  bool qskip = (q0 < 384) ? (TL <= q0) : (IL <= q0 - 384);
  if (qskip) {
    h16x8 z = {};
    for (int c = t; c < 1536; c += 256) {
      int row = c / 48, v8 = (c % 48) * 8;
      *(h16x8*)&Qp[(size_t)(q0+row)*384 + v8] = z;
    }
    return;
  }

  h16x8 aq[2][12];
  #pragma unroll
  for (int m = 0; m < 2; ++m)
    #pragma unroll
    for (int ks = 0; ks < 12; ++ks)
      aq[m][ks] = *(const h16x8*)&Qp[(size_t)(q0 + m*16 + li)*384 + ks*32 + lg*8];

  int kbase = w * 128;
  int LIMw = (w < 3) ? TL : (384 + IL);
  int nvf = (LIMw - kbase + 15) >> 4;
  nvf = nvf < 0 ? 0 : (nvf > 8 ? 8 : nvf);
  for (int nf = 0; nf < nvf; ++nf) {
    int kcol = kbase + nf*16;
    f32x4 acc0 = {0,0,0,0}, acc1 = {0,0,0,0};
    #pragma unroll
    for (int ks = 0; ks < 12; ++ks) {
      h16x8 bk = *(const h16x8*)&Kp[(size_t)(kcol + li)*384 + ks*32 + lg*8];
      acc0 = MFMA(aq[0][ks], bk, acc0);
      acc1 = MFMA(aq[1][ks], bk, acc1);
    }
    #pragma unroll
    for (int r = 0; r < 4; ++r) {
      int c = kcol + li;
      int row0 = lg*4 + r;
      float v0 = acc0[r];
      if (v0 == 0.0f || (q0 + row0) == c) v0 = -__builtin_inff();
      S[row0*516 + c] = v0;
      int row1 = 16 + lg*4 + r;
      float v1 = acc1[r];
      if (v1 == 0.0f || (q0 + row1) == c) v1 = -__builtin_inff();
      S[row1*516 + c] = v1;
    }
  }
  for (int nf = nvf; nf < 8; ++nf) {
    int c = kbase + nf*16 + li;
    #pragma unroll
    for (int r = 0; r < 4; ++r) {
      S[(lg*4 + r)*516 + c] = -__builtin_inff();
      S[(16 + lg*4 + r)*516 + c] = -__builtin_inff();
    }
  }
  __syncthreads();
  {
    int row = t >> 3, ci = t & 7;
    float mx = -3e38f;
    for (int j = 0; j < 64; ++j) mx = fmaxf(mx, S[row*516 + ci + j*8]);
    mx = fmaxf(mx, __shfl_xor(mx, 1));
    mx = fmaxf(mx, __shfl_xor(mx, 2));
    mx = fmaxf(mx, __shfl_xor(mx, 4));
    float sum = 0.0f;
    for (int j = 0; j < 64; ++j) {
      float e = __expf(S[row*516 + ci + j*8] - mx);
      S[row*516 + ci + j*8] = e;
      sum += e;
    }
    sum += __shfl_xor(sum, 1);
    sum += __shfl_xor(sum, 2);
    sum += __shfl_xor(sum, 4);
    if (ci == 0) rowscale[row] = 1.0f / (sum > 0.0f ? sum : 1.0f);
  }
  __syncthreads();
  f32x4 oacc[2][6] = {};
  int v0w = w * 96;
  auto pv = [&](int kt) {
    int k0 = kt * 32;
    h16x8 bv[6];
    #pragma unroll
    for (int n = 0; n < 6; ++n)
      bv[n] = *(const h16x8*)&Vp[(size_t)(v0w + n*16 + li)*512 + k0 + lg*8];
    #pragma unroll
    for (int m = 0; m < 2; ++m) {
      int row = m*16 + li;
      f32x4 p0 = *(const f32x4*)&S[row*516 + k0 + lg*8];
      f32x4 p1 = *(const f32x4*)&S[row*516 + k0 + lg*8 + 4];
      h16x8 pa;
      pa[0]=(h16)p0[0]; pa[1]=(h16)p0[1]; pa[2]=(h16)p0[2]; pa[3]=(h16)p0[3];
      pa[4]=(h16)p1[0]; pa[5]=(h16)p1[1]; pa[6]=(h16)p1[2]; pa[7]=(h16)p1[3];
      #pragma unroll
      for (int n = 0; n < 6; ++n)
        oacc[m][n] = MFMA(pa, bv[n], oacc[m][n]);
    }
  };
  int n1 = (TL + 31) >> 5; n1 = n1 > 12 ? 12 : n1;
  int n2 = (IL + 31) >> 5; n2 = n2 > 4 ? 4 : n2;
  for (int kt = 0; kt < n1; ++kt) pv(kt);
  for (int kt = 12; kt < 12 + n2; ++kt) pv(kt);
  #pragma unroll
  for (int m = 0; m < 2; ++m)
    #pragma unroll
    for (int n = 0; n < 6; ++n)
      #pragma unroll
      for (int r = 0; r < 4; ++r) {
        int row = m*16 + lg*4 + r;
        int col = v0w + n*16 + li;
        Qp[(size_t)(q0 + row)*384 + col] = (h16)(oacc[m][n][r] * rowscale[row]);
      }
}

// ---------------- attention stage 2 + mean (branch-free skips)
__global__ __launch_bounds__(256) void k_attn2(
    const float* __restrict__ query, const h16* __restrict__ keys,
    const h16* __restrict__ valsT, const int* __restrict__ qlen,
    const int* __restrict__ tlen, const int* __restrict__ ilen,
    float* __restrict__ out)
{
  __shared__ __align__(16) float S[32*516];
  __shared__ __align__(16) h16 UB[32*776];
  __shared__ float rowscale[32];
  int b = blockIdx.x;
  const float* Qp = query + (size_t)b*24*768;
  const h16* Kp = keys + (size_t)b*512*768;
  const h16* Vp = valsT + (size_t)b*768*512;
  int t = threadIdx.x, lane = t & 63, w = t >> 6;
  int lg = lane >> 4, li = lane & 15;
  int ql = qlen[b];
  int TL = tlen[b], IL = ilen[b];
  for (int c = t; c < 3072; c += 256) {
    int row = c / 96, vv = (c % 96) * 8;
    h16x8 a = {};
    if (row < 24 && row < ql) {
      f32x4 f0 = *(const f32x4*)&Qp[(size_t)row*768 + vv];
      f32x4 f1 = *(const f32x4*)&Qp[(size_t)row*768 + vv + 4];
      a[0]=(h16)f0[0]; a[1]=(h16)f0[1]; a[2]=(h16)f0[2]; a[3]=(h16)f0[3];
      a[4]=(h16)f1[0]; a[5]=(h16)f1[1]; a[6]=(h16)f1[2]; a[7]=(h16)f1[3];
    }
    *(h16x8*)&UB[row*776 + vv] = a;
  }
  __syncthreads();
  int kbase = w * 128;
  int LIMw = (w < 3) ? TL : (384 + IL);
  int nvf = (LIMw - kbase + 15) >> 4;
  nvf = nvf < 0 ? 0 : (nvf > 8 ? 8 : nvf);
  for (int nf = 0; nf < nvf; ++nf) {
    int kcol = kbase + nf*16;
    f32x4 acc0 = {0,0,0,0}, acc1 = {0,0,0,0};
    #pragma unroll
    for (int ks = 0; ks < 24; ++ks) {
      h16x8 a0 = *(const h16x8*)&UB[(li)*776      + ks*32 + lg*8];
      h16x8 a1 = *(const h16x8*)&UB[(16 + li)*776 + ks*32 + lg*8];
      h16x8 bk = *(const h16x8*)&Kp[(size_t)(kcol + li)*768 + ks*32 + lg*8];
      acc0 = MFMA(a0, bk, acc0);
      acc1 = MFMA(a1, bk, acc1);
    }
    #pragma unroll
    for (int r = 0; r < 4; ++r) {
      int c = kcol + li;
      float v0 = acc0[r];
      if (v0 == 0.0f) v0 = -__builtin_inff();
      S[(lg*4 + r)*516 + c] = v0;
      float v1 = acc1[r];
      if (v1 == 0.0f) v1 = -__builtin_inff();
      S[(16 + lg*4 + r)*516 + c] = v1;
    }
  }
  for (int nf = nvf; nf < 8; ++nf) {
    int c = kbase + nf*16 + li;
    #pragma unroll
    for (int r = 0; r < 4; ++r) {
      S[(lg*4 + r)*516 + c] = -__builtin_inff();
      S[(16 + lg*4 + r)*516 + c] = -__builtin_inff();
    }
  }
  __syncthreads();
  {
    int row = t >> 3, ci = t & 7;
    float mx = -3e38f;
    for (int j = 0; j < 64; ++j) mx = fmaxf(mx, S[row*516 + ci + j*8]);
    mx = fmaxf(mx, __shfl_xor(mx, 1));
    mx = fmaxf(mx, __shfl_xor(mx, 2));
    mx = fmaxf(mx, __shfl_xor(mx, 4));
    float sum = 0.0f;
    for (int j = 0; j < 64; ++j) {
      float e = __expf(S[row*516 + ci + j*8] - mx);
      S[row*516 + ci + j*8] = e;
      sum += e;
    }
    sum += __shfl_xor(sum, 1);
    sum += __shfl_xor(sum, 2);
    sum += __shfl_xor(sum, 4);
    if (ci == 0) rowscale[row] = 1.0f / (sum > 0.0f ? sum : 1.0f);
  }
  __syncthreads();
  int n1 = (TL + 31) >> 5; n1 = n1 > 12 ? 12 : n1;
  int n2 = (IL + 31) >> 5; n2 = n2 > 4 ? 4 : n2;
  for (int vh = 0; vh < 2; ++vh) {
    f32x4 oacc[2][6] = {};
    auto pv = [&](int kt) {
      int k0 = kt * 32;
      h16x8 bv[6];
      #pragma unroll
      for (int n = 0; n < 6; ++n)
        bv[n] = *(const h16x8*)&Vp[(size_t)(vh*384 + w*96 + n*16 + li)*512 + k0 + lg*8];
      #pragma unroll
      for (int m = 0; m < 2; ++m) {
        int row = m*16 + li;
        f32x4 p0 = *(const f32x4*)&S[row*516 + k0 + lg*8];
        f32x4 p1 = *(const f32x4*)&S[row*516 + k0 + lg*8 + 4];
        h16x8 pa;
        pa[0]=(h16)p0[0]; pa[1]=(h16)p0[1]; pa[2]=(h16)p0[2]; pa[3]=(h16)p0[3];
        pa[4]=(h16)p1[0]; pa[5]=(h16)p1[1]; pa[6]=(h16)p1[2]; pa[7]=(h16)p1[3];
        #pragma unroll
        for (int n = 0; n < 6; ++n)
          oacc[m][n] = MFMA(pa, bv[n], oacc[m][n]);
      }
    };
    for (int kt = 0; kt < n1; ++kt) pv(kt);
    for (int kt = 12; kt < 12 + n2; ++kt) pv(kt);
    #pragma unroll
    for (int n = 0; n < 6; ++n) {
      float cs = 0.0f;
      #pragma unroll
      for (int m = 0; m < 2; ++m)
        #pragma unroll
        for (int r = 0; r < 4; ++r)
          cs += oacc[m][n][r] * rowscale[m*16 + lg*4 + r];
      cs += __shfl_xor(cs, 16);
      cs += __shfl_xor(cs, 32);
      if (lg == 0) out[(size_t)b*768 + vh*384 + w*96 + n*16 + li] = cs * (1.0f/24.0f);
    }
  }
}

extern "C" void kernel_launch(void* const* d_in, const int* in_sizes, int n_in,
                              void* d_out, int out_size, void* d_ws, size_t ws_size,
                              hipStream_t stream)
{
  (void)in_sizes; (void)n_in;
  const float* text  = (const float*)d_in[0];
  const float* images= (const float*)d_in[1];
  const float* query = (const float*)d_in[2];
  const float* ln_g  = (const float*)d_in[3];
  const float* ln_b  = (const float*)d_in[4];
  const float* Wsq = (const float*)d_in[5];
  const float* bsq = (const float*)d_in[6];
  const float* Wiq = (const float*)d_in[7];
  const float* biq = (const float*)d_in[8];
  const float* Wsk = (const float*)d_in[9];
  const float* bsk = (const float*)d_in[10];
  const float* Wik = (const float*)d_in[11];
  const float* bik = (const float*)d_in[12];
  const float* Wsv = (const float*)d_in[13];
  const float* bsv = (const float*)d_in[14];
  const float* Wiv = (const float*)d_in[15];
  const float* biv = (const float*)d_in[16];
  const float* Wkp = (const float*)d_in[17];
  const float* bkp = (const float*)d_in[18];
  const float* Wvp = (const float*)d_in[19];
  const float* bvp = (const float*)d_in[20];
  const int* tlen = (const int*)d_in[21];
  const int* ilen = (const int*)d_in[22];
  const int* qlen = (const int*)d_in[23];

  // ws: [0,256KB) stats; [256KB,+9.4MB) weights; 3x50.33MB Qb/Kb/Vb; [+48MB XN if room]
  const size_t NEED1 = 160694272;
  const size_t NEED2 = NEED1 + 50331648;
  if (ws_size < NEED1) {
    k_diag<<<dim3((out_size+255)/256), dim3(256), 0, stream>>>((float*)d_out, out_size, 1.0e6f);
    return;
  }
  float* muv = (float*)d_ws;
  float* rsd = muv + 32768;
  h16* wb = (h16*)((char*)d_ws + 262144);
  const size_t WSZ = 589824;
  const size_t TSZ = (size_t)32768*768;
  h16* Qb = wb + 8*WSZ;
  h16* Kb = Qb + TSZ;
  h16* Vb = Kb + TSZ;
  h16* XNb = (h16*)((char*)d_ws + NEED1);

  dim3 blk(256);
  k_wprep_all<<<dim3(24,24,14), blk, 0, stream>>>(Wsq, Wiq, Wsk, Wik, Wsv, Wiv, Wkp, Wvp, wb);

  if (ws_size >= NEED2) {
    // main path: materialized XN + global_load_lds GEMMs
    k_ln<<<dim3(32768), blk, 0, stream>>>(text, images, ln_g, ln_b, XNb);
    k_gemmf2<0><<<dim3(4608), blk, 0, stream>>>(XNb, wb,
        bsq, biq, bsk, bik, bsv, biv, bkp, bvp, Qb, Kb, Vb, tlen, ilen);
  } else {
    // fallback: LN-on-the-fly QKV
    k_lnstat<<<dim3(32768), blk, 0, stream>>>(text, images, muv, rsd);
    k_gemmf_fb<<<dim3(4608), blk, 0, stream>>>(text, images, muv, rsd,
        ln_g, ln_b, wb, bsq, biq, bsk, bik, bsv, biv, Qb, Kb, Vb, tlen, ilen);
  }

  k_attn1<<<dim3(16,128), blk, 0, stream>>>(Qb, Kb, Vb, tlen, ilen);

  k_gemmf2<2><<<dim3(3072), blk, 0, stream>>>(Qb, wb,
      bsq, biq, bsk, bik, bsv, biv, bkp, bvp, Kb, Vb, nullptr, tlen, ilen);

  k_attn2<<<dim3(64), blk, 0, stream>>>(query, Kb, Vb, qlen, tlen, ilen, (float*)d_out);
}

// Round 7
// 530.754 us; speedup vs baseline: 3.1258x; 1.0750x over previous
//
#include <hip/hip_runtime.h>
#include <hip/hip_bf16.h>

typedef _Float16 h16;
typedef _Float16 h16x8 __attribute__((ext_vector_type(8)));
typedef _Float16 h16x4 __attribute__((ext_vector_type(4)));
typedef float    f32x4 __attribute__((ext_vector_type(4)));

#define MFMA(a,b,c) __builtin_amdgcn_mfma_f32_16x16x32_f16((a),(b),(c),0,0,0)

// H=2 B=64 LT=384 LI=128 L=512 D=768 K=V=384 DK=DV=768 LQ=24

typedef __attribute__((address_space(1))) const void gas_void;
typedef __attribute__((address_space(3))) void las_void;
__device__ __forceinline__ void gld16(void* l, const void* g) {
  __builtin_amdgcn_global_load_lds((gas_void*)g, (las_void*)l, 16, 0, 0);
}

__global__ __launch_bounds__(256) void k_diag(float* out, int n, float val) {
  int i = blockIdx.x * 256 + threadIdx.x;
  if (i < n) out[i] = val;
}

// ---------------- LayerNorm -> fp16 XN[b*512+l][768]
__global__ __launch_bounds__(256) void k_ln(
    const float* __restrict__ text, const float* __restrict__ images,
    const float* __restrict__ g, const float* __restrict__ be,
    h16* __restrict__ xn)
{
  int row = blockIdx.x;
  int b = row >> 9, l = row & 511;
  const float* src = (l < 384) ? (text + ((size_t)b*384 + l)*768)
                               : (images + ((size_t)b*128 + (l-384))*768);
  int t = threadIdx.x;
  float x0 = src[t], x1 = src[t+256], x2 = src[t+512];
  __shared__ float red[8];
  float s = x0 + x1 + x2;
  #pragma unroll
  for (int m = 32; m; m >>= 1) s += __shfl_xor(s, m);
  int wid = t >> 6;
  if ((t & 63) == 0) red[wid] = s;
  __syncthreads();
  float mu = (red[0]+red[1]+red[2]+red[3]) * (1.0f/768.0f);
  float d0 = x0-mu, d1 = x1-mu, d2 = x2-mu;
  float v = d0*d0 + d1*d1 + d2*d2;
  #pragma unroll
  for (int m = 32; m; m >>= 1) v += __shfl_xor(v, m);
  if ((t & 63) == 0) red[4+wid] = v;
  __syncthreads();
  float var = (red[4]+red[5]+red[6]+red[7]) * (1.0f/768.0f);
  float rstd = rsqrtf(var + 1e-5f);
  h16* dst = xn + (size_t)row * 768;
  dst[t]     = (h16)(d0*rstd*g[t]     + be[t]);
  dst[t+256] = (h16)(d1*rstd*g[t+256] + be[t+256]);
  dst[t+512] = (h16)(d2*rstd*g[t+512] + be[t+512]);
}

// ---------------- LayerNorm stats only (fallback path)
__global__ __launch_bounds__(256) void k_lnstat(
    const float* __restrict__ text, const float* __restrict__ images,
    float* __restrict__ muv, float* __restrict__ rsd)
{
  int row = blockIdx.x;
  int b = row >> 9, l = row & 511;
  const float* src = (l < 384) ? (text + ((size_t)b*384 + l)*768)
                               : (images + ((size_t)b*128 + (l-384))*768);
  int t = threadIdx.x;
  float x0 = src[t], x1 = src[t+256], x2 = src[t+512];
  __shared__ float red[8];
  float s = x0 + x1 + x2;
  #pragma unroll
  for (int m = 32; m; m >>= 1) s += __shfl_xor(s, m);
  int wid = t >> 6;
  if ((t & 63) == 0) red[wid] = s;
  __syncthreads();
  float mu = (red[0]+red[1]+red[2]+red[3]) * (1.0f/768.0f);
  float d0 = x0-mu, d1 = x1-mu, d2 = x2-mu;
  float v = d0*d0 + d1*d1 + d2*d2;
  #pragma unroll
  for (int m = 32; m; m >>= 1) v += __shfl_xor(v, m);
  if ((t & 63) == 0) red[4+wid] = v;
  __syncthreads();
  if (t == 0) {
    float var = (red[4]+red[5]+red[6]+red[7]) * (1.0f/768.0f);
    muv[row] = mu;
    rsd[row] = rsqrtf(var + 1e-5f);
  }
}

// ---------------- all weight transposes in ONE launch
__global__ __launch_bounds__(256) void k_wprep_all(
    const float* __restrict__ Wsq, const float* __restrict__ Wiq,
    const float* __restrict__ Wsk, const float* __restrict__ Wik,
    const float* __restrict__ Wsv, const float* __restrict__ Wiv,
    const float* __restrict__ Wkp, const float* __restrict__ Wvp,
    h16* __restrict__ wb)
{
  const size_t WSZ = 589824;
  int z = blockIdx.z;
  const float* src; h16* dst;
  int cols;
  if (z < 12) {
    if (blockIdx.x >= 12) return;
    int w = z >> 1, m = z & 1;
    const float* s6[6] = {Wsq, Wiq, Wsk, Wik, Wsv, Wiv};
    src = s6[w] + (size_t)m * 768 * 384;
    dst = wb + (size_t)w * WSZ + (size_t)m * 384 * 768;
    cols = 384;
  } else {
    src = (z == 12) ? Wkp : Wvp;
    dst = wb + (size_t)(6 + (z - 12)) * WSZ;
    cols = 768;
  }
  __shared__ float tile[32][33];
  int d0 = blockIdx.y * 32;
  int c0 = blockIdx.x * 32;
  int tx = threadIdx.x & 31, ty = threadIdx.x >> 5;
  #pragma unroll
  for (int i = 0; i < 32; i += 8)
    tile[ty+i][tx] = src[(size_t)(d0+ty+i)*cols + c0 + tx];
  __syncthreads();
  #pragma unroll
  for (int i = 0; i < 32; i += 8)
    dst[(size_t)(c0+ty+i)*768 + d0 + tx] = (h16)tile[tx][ty+i];
}

#define HOFF ((size_t)64*512*384)

// ---------------- GEMM: double-buffered global_load_lds, XOR-swizzled LDS
// AMODE 0: QKV. A = XN fp16 [row][768]. N = 2304 (widx 0 Q, 1 K, 2 V^T)
// AMODE 2: keys/vals. A = album@Qb (Q-layout head-split). N = 1536
template<int AMODE>
__global__ __launch_bounds__(256) void k_gemmf2(
    const h16* __restrict__ Asrc, const h16* __restrict__ wb,
    const float* __restrict__ bsq, const float* __restrict__ biq,
    const float* __restrict__ bsk, const float* __restrict__ bik,
    const float* __restrict__ bsv, const float* __restrict__ biv,
    const float* __restrict__ bkp, const float* __restrict__ bvp,
    h16* __restrict__ O0, h16* __restrict__ O1, h16* __restrict__ O2,
    const int* __restrict__ tlen, const int* __restrict__ ilen)
{
  constexpr int NT = (AMODE == 0) ? 18 : 12;
  __shared__ __align__(16) h16 As[2][128*64];
  __shared__ __align__(16) h16 Bs[2][128*64];
  const size_t WSZ = 589824;
  int bid = blockIdx.x;
  int xcd = bid & 7, slot = bid >> 3;     // XCD-chunked: nt fastest per XCD
  int mt = xcd * 32 + slot / NT;
  int nt = slot % NT;
  int m0 = mt << 7;
  int b = m0 >> 9, l0 = m0 & 511;
  int TL = tlen[b], IL = ilen[b];
  bool skiptile = (l0 < 384) && (TL <= l0);
  int gc0 = nt << 7;
  int widx = gc0 / 768;
  int ncol0 = gc0 % 768;
  bool isimg = (l0 >= 384);

  const h16* BT;
  const float* bias;
  if constexpr (AMODE == 0) {
    BT = wb + ((size_t)(2*widx) + (isimg ? 1 : 0)) * WSZ;
    const float* bt6[6] = {bsq, biq, bsk, bik, bsv, biv};
    bias = bt6[2*widx + (isimg ? 1 : 0)];
  } else {
    BT = wb + (size_t)(6 + widx) * WSZ;
    bias = widx ? bvp : bkp;
  }

  int t = threadIdx.x;
  int lane = t & 63, wid = t >> 6;
  int wm = wid >> 1, wn = wid & 1;
  int lg = lane >> 4, li = lane & 15;

  f32x4 acc[4][4] = {};

  if (!skiptile) {
    // staging: thread t covers chunk ci = h*256+t; LDS dest chunk ci (linear);
    // global SOURCE chunk column pre-swizzled: csrc = (ci&7) ^ (row&7)
    const h16* pA[4]; const h16* pB[4];
    h16* dA[4]; h16* dB[4];
    #pragma unroll
    for (int h = 0; h < 4; ++h) {
      int ci = h*256 + t;
      int row = ci >> 3;
      int cs = (ci & 7) ^ (row & 7);
      if constexpr (AMODE == 0)
        pA[h] = Asrc + (size_t)(m0 + row)*768 + cs*8;
      else
        pA[h] = Asrc + ((size_t)b*512 + l0 + row)*384 + cs*8;
      pB[h] = BT + (size_t)(ncol0 + row)*768 + cs*8;
      dA[h] = &As[0][(h*256 + wid*64)*8];     // wave-uniform dest base
      dB[h] = &Bs[0][(h*256 + wid*64)*8];
    }
    // per-lane swizzled read bases
    const char* baA = (const char*)&As[0][0] + (wm*64 + li)*128;
    const char* baB = (const char*)&Bs[0][0] + (wn*64 + li)*128;
    int x0 = (lg ^ (li & 7)) << 4;

    // prologue: stage tile 0 into buf 0
    #pragma unroll
    for (int h = 0; h < 4; ++h) {
      gld16(dA[h], pA[h]);
      gld16(dB[h], pB[h]);
    }
    __syncthreads();

    #pragma unroll
    for (int kk = 0; kk < 12; ++kk) {
      const int cur = kk & 1;
      // prefetch next tile into buf cur^1 (flies under compute)
      if (kk < 11) {
        int ktE = (kk + 1) * 64;
        size_t aoff = (size_t)ktE;
        if constexpr (AMODE == 2) { if (ktE >= 384) aoff += HOFF - 384; }
        #pragma unroll
        for (int h = 0; h < 4; ++h) {
          gld16(dA[h] + (cur^1)*8192, pA[h] + aoff);
          gld16(dB[h] + (cur^1)*8192, pB[h] + ktE);
        }
      }
      // compute buf cur
      const char* cA = baA + cur*16384;
      const char* cB = baB + cur*16384;
      #pragma unroll
      for (int ks = 0; ks < 2; ++ks) {
        int xo = x0 ^ (ks << 6);
        h16x8 af[4], bf[4];
        #pragma unroll
        for (int i = 0; i < 4; ++i) {
          af[i] = *(const h16x8*)(cA + i*2048 + xo);
          bf[i] = *(const h16x8*)(cB + i*2048 + xo);
        }
        #pragma unroll
        for (int i = 0; i < 4; ++i)
          #pragma unroll
          for (int j = 0; j < 4; ++j)
            acc[i][j] = MFMA(af[i], bf[j], acc[i][j]);
      }
      __syncthreads();   // drains prefetch vmcnt + read lgkm; one barrier/tile
    }
  }

  // epilogue: bias, pad-zero, route
  bool vroute = (AMODE == 0) ? (widx == 2) : (widx == 1);
  h16* dsc = (AMODE == 0) ? (widx == 0 ? O0 : O1) : O0;
  h16* dsv = (AMODE == 0) ? O2 : O1;
  #pragma unroll
  for (int i = 0; i < 4; ++i)
    #pragma unroll
    for (int j = 0; j < 4; ++j) {
      int colL = wn*64 + j*16 + li;
      int col_in = ncol0 + colL;
      float bv = bias[col_in];
      int lb = l0 + wm*64 + i*16 + lg*4;
      int hh = (col_in >= 384) ? 1 : 0;
      int kk = col_in - hh*384;
      if (vroute) {
        h16x4 pk;
        #pragma unroll
        for (int r = 0; r < 4; ++r) {
          int l = lb + r;
          float v = acc[i][j][r] + bv;
          bool pad = (l < 384) ? (l >= TL) : ((l-384) >= IL);
          pk[r] = (h16)(pad ? 0.0f : v);
        }
        size_t oi;
        if constexpr (AMODE == 0)
          oi = (((size_t)(hh*64 + b))*384 + kk)*512 + lb;
        else
          oi = ((size_t)b*768 + col_in)*512 + lb;
        *(h16x4*)&dsv[oi] = pk;
      } else {
        #pragma unroll
        for (int r = 0; r < 4; ++r) {
          int l = lb + r;
          float v = acc[i][j][r] + bv;
          bool pad = (l < 384) ? (l >= TL) : ((l-384) >= IL);
          if (pad) v = 0.0f;
          size_t oi;
          if constexpr (AMODE == 0)
            oi = (((size_t)(hh*64 + b))*512 + l)*384 + kk;
          else
            oi = ((size_t)b*512 + l)*768 + col_in;
          dsc[oi] = (h16)v;
        }
      }
    }
}

// ---------------- FALLBACK GEMM (LN on the fly), used if ws too small
#define LDSKg 72
__global__ __launch_bounds__(256) void k_gemmf_fb(
    const float* __restrict__ Atext, const float* __restrict__ Aimg,
    const float* __restrict__ muv, const float* __restrict__ rsd,
    const float* __restrict__ gam, const float* __restrict__ bet,
    const h16* __restrict__ wb,
    const float* __restrict__ bsq, const float* __restrict__ biq,
    const float* __restrict__ bsk, const float* __restrict__ bik,
    const float* __restrict__ bsv, const float* __restrict__ biv,
    h16* __restrict__ O0, h16* __restrict__ O1, h16* __restrict__ O2,
    const int* __restrict__ tlen, const int* __restrict__ ilen)
{
  constexpr int NT = 18;
  __shared__ __align__(16) h16 As[128*LDSKg];
  __shared__ __align__(16) h16 Bs[128*LDSKg];
  const size_t WSZ = 589824;
  int bid = blockIdx.x;
  int xcd = bid & 7, slot = bid >> 3;
  int mt = xcd * 32 + slot / NT;
  int nt = slot % NT;
  int m0 = mt << 7;
  int b = m0 >> 9, l0 = m0 & 511;
  int TL = tlen[b], IL = ilen[b];
  bool skiptile = (l0 < 384) && (TL <= l0);
  int gc0 = nt << 7;
  int widx = gc0 / 768;
  int ncol0 = gc0 % 768;
  bool isimg = (l0 >= 384);
  const h16* BT = wb + ((size_t)(2*widx) + (isimg ? 1 : 0)) * WSZ;
  const float* bt6[6] = {bsq, biq, bsk, bik, bsv, biv};
  const float* bias = bt6[2*widx + (isimg ? 1 : 0)];

  int t = threadIdx.x;
  int lane = t & 63, wid = t >> 6;
  int wm = wid >> 1, wn = wid & 1;
  int lg = lane >> 4, li = lane & 15;
  int sr = t >> 3, sc8 = (t & 7) * 8;
  f32x4 acc[4][4] = {};
  if (!skiptile) {
    const float* af32[4];
    float amu[4], ars[4];
    const h16* brow[4];
    #pragma unroll
    for (int half = 0; half < 4; ++half) {
      int r = sr + half*32;
      int l = l0 + r;
      af32[half] = (l < 384) ? (Atext + ((size_t)b*384 + l)*768)
                             : (Aimg  + ((size_t)b*128 + (l-384))*768);
      amu[half] = muv[m0 + r]; ars[half] = rsd[m0 + r];
      brow[half] = BT + (size_t)(ncol0 + r)*768;
    }
    for (int kt = 0; kt < 768; kt += 64) {
      int d = kt + sc8;
      f32x4 g0 = *(const f32x4*)&gam[d], g1 = *(const f32x4*)&gam[d+4];
      f32x4 e0 = *(const f32x4*)&bet[d], e1 = *(const f32x4*)&bet[d+4];
      #pragma unroll
      for (int half = 0; half < 4; ++half) {
        int r = sr + half*32;
        f32x4 x0 = *(const f32x4*)&af32[half][d];
        f32x4 x1 = *(const f32x4*)&af32[half][d+4];
        float mu = amu[half], rs = ars[half];
        h16x8 o;
        #pragma unroll
        for (int j = 0; j < 4; ++j) o[j]   = (h16)((x0[j]-mu)*rs*g0[j] + e0[j]);
        #pragma unroll
        for (int j = 0; j < 4; ++j) o[4+j] = (h16)((x1[j]-mu)*rs*g1[j] + e1[j]);
        *(h16x8*)&As[r*LDSKg + sc8] = o;
        *(uint4*)&Bs[r*LDSKg + sc8] = *(const uint4*)&brow[half][d];
      }
      __syncthreads();
      #pragma unroll
      for (int ks = 0; ks < 2; ++ks) {
        int kc = ks*32 + lg*8;
        h16x8 af[4], bf[4];
        #pragma unroll
        for (int i = 0; i < 4; ++i) {
          af[i] = *(const h16x8*)&As[(wm*64 + i*16 + li)*LDSKg + kc];
          bf[i] = *(const h16x8*)&Bs[(wn*64 + i*16 + li)*LDSKg + kc];
        }
        #pragma unroll
        for (int i = 0; i < 4; ++i)
          #pragma unroll
          for (int j = 0; j < 4; ++j)
            acc[i][j] = MFMA(af[i], bf[j], acc[i][j]);
      }
      __syncthreads();
    }
  }
  bool vroute = (widx == 2);
  h16* dsc = (widx == 0 ? O0 : O1);
  #pragma unroll
  for (int i = 0; i < 4; ++i)
    #pragma unroll
    for (int j = 0; j < 4; ++j) {
      int colL = wn*64 + j*16 + li;
      int col_in = ncol0 + colL;
      float bv = bias[col_in];
      int lb = l0 + wm*64 + i*16 + lg*4;
      int hh = (col_in >= 384) ? 1 : 0;
      int kk = col_in - hh*384;
      if (vroute) {
        h16x4 pk;
        #pragma unroll
        for (int r = 0; r < 4; ++r) {
          int l = lb + r;
          float v = acc[i][j][r] + bv;
          bool pad = (l < 384) ? (l >= TL) : ((l-384) >= IL);
          pk[r] = (h16)(pad ? 0.0f : v);
        }
        size_t oi = (((size_t)(hh*64 + b))*384 + kk)*512 + lb;
        *(h16x4*)&O2[oi] = pk;
      } else {
        #pragma unroll
        for (int r = 0; r < 4; ++r) {
          int l = lb + r;
          float v = acc[i][j][r] + bv;
          bool pad = (l < 384) ? (l >= TL) : ((l-384) >= IL);
          if (pad) v = 0.0f;
          size_t oi = (((size_t)(hh*64 + b))*512 + l)*384 + kk;
          dsc[oi] = (h16)v;
        }
      }
    }
}

// ---------------- attention stage 1 (branch-free padding skips)
__global__ __launch_bounds__(256) void k_attn1(
    h16* Qb, const h16* __restrict__ Kb, const h16* __restrict__ Vt,
    const int* __restrict__ tlen, const int* __restrict__ ilen)
{
  __shared__ __align__(16) float S[32*516];
  __shared__ float rowscale[32];
  int hb = blockIdx.y;
  int q0 = blockIdx.x * 32;
  int b = hb & 63;
  int TL = tlen[b], IL = ilen[b];
  h16* Qp = Qb + (size_t)hb * 512 * 384;
  const h16* Kp = Kb + (size_t)hb * 512 * 384;
  const h16* Vp = Vt + (size_t)hb * 384 * 512;
  int t = threadIdx.x, lane = t & 63, w = t >> 6;
  int lg = lane >> 4, li = lane & 15;

  bool qskip = (q0 < 384) ? (TL <= q0) : (IL <= q0 - 384);
  if (qskip) {
    h16x8 z = {};
    for (int c = t; c < 1536; c += 256) {
      int row = c / 48, v8 = (c % 48) * 8;
      *(h16x8*)&Qp[(size_t)(q0+row)*384 + v8] = z;
    }
    return;
  }

  h16x8 aq[2][12];
  #pragma unroll
  for (int m = 0; m < 2; ++m)
    #pragma unroll
    for (int ks = 0; ks < 12; ++ks)
      aq[m][ks] = *(const h16x8*)&Qp[(size_t)(q0 + m*16 + li)*384 + ks*32 + lg*8];

  int kbase = w * 128;
  int LIMw = (w < 3) ? TL : (384 + IL);
  int nvf = (LIMw - kbase + 15) >> 4;
  nvf = nvf < 0 ? 0 : (nvf > 8 ? 8 : nvf);
  for (int nf = 0; nf < nvf; ++nf) {
    int kcol = kbase + nf*16;
    f32x4 acc0 = {0,0,0,0}, acc1 = {0,0,0,0};
    #pragma unroll
    for (int ks = 0; ks < 12; ++ks) {
      h16x8 bk = *(const h16x8*)&Kp[(size_t)(kcol + li)*384 + ks*32 + lg*8];
      acc0 = MFMA(aq[0][ks], bk, acc0);
      acc1 = MFMA(aq[1][ks], bk, acc1);
    }
    #pragma unroll
    for (int r = 0; r < 4; ++r) {
      int c = kcol + li;
      int row0 = lg*4 + r;
      float v0 = acc0[r];
      if (v0 == 0.0f || (q0 + row0) == c) v0 = -__builtin_inff();
      S[row0*516 + c] = v0;
      int row1 = 16 + lg*4 + r;
      float v1 = acc1[r];
      if (v1 == 0.0f || (q0 + row1) == c) v1 = -__builtin_inff();
      S[row1*516 + c] = v1;
    }
  }
  for (int nf = nvf; nf < 8; ++nf) {
    int c = kbase + nf*16 + li;
    #pragma unroll
    for (int r = 0; r < 4; ++r) {
      S[(lg*4 + r)*516 + c] = -__builtin_inff();
      S[(16 + lg*4 + r)*516 + c] = -__builtin_inff();
    }
  }
  __syncthreads();
  {
    int row = t >> 3, ci = t & 7;
    float mx = -3e38f;
    for (int j = 0; j < 64; ++j) mx = fmaxf(mx, S[row*516 + ci + j*8]);
    mx = fmaxf(mx, __shfl_xor(mx, 1));
    mx = fmaxf(mx, __shfl_xor(mx, 2));
    mx = fmaxf(mx, __shfl_xor(mx, 4));
    float sum = 0.0f;
    for (int j = 0; j < 64; ++j) {
      float e = __expf(S[row*516 + ci + j*8] - mx);
      S[row*516 + ci + j*8] = e;
      sum += e;
    }
    sum += __shfl_xor(sum, 1);
    sum += __shfl_xor(sum, 2);
    sum += __shfl_xor(sum, 4);
    if (ci == 0) rowscale[row] = 1.0f / (sum > 0.0f ? sum : 1.0f);
  }
  __syncthreads();
  f32x4 oacc[2][6] = {};
  int v0w = w * 96;
  auto pv = [&](int kt) {
    int k0 = kt * 32;
    h16x8 bv[6];
    #pragma unroll
    for (int n = 0; n < 6; ++n)
      bv[n] = *(const h16x8*)&Vp[(size_t)(v0w + n*16 + li)*512 + k0 + lg*8];
    #pragma unroll
    for (int m = 0; m < 2; ++m) {
      int row = m*16 + li;
      f32x4 p0 = *(const f32x4*)&S[row*516 + k0 + lg*8];
      f32x4 p1 = *(const f32x4*)&S[row*516 + k0 + lg*8 + 4];
      h16x8 pa;
      pa[0]=(h16)p0[0]; pa[1]=(h16)p0[1]; pa[2]=(h16)p0[2]; pa[3]=(h16)p0[3];
      pa[4]=(h16)p1[0]; pa[5]=(h16)p1[1]; pa[6]=(h16)p1[2]; pa[7]=(h16)p1[3];
      #pragma unroll
      for (int n = 0; n < 6; ++n)
        oacc[m][n] = MFMA(pa, bv[n], oacc[m][n]);
    }
  };
  int n1 = (TL + 31) >> 5; n1 = n1 > 12 ? 12 : n1;
  int n2 = (IL + 31) >> 5; n2 = n2 > 4 ? 4 : n2;
  for (int kt = 0; kt < n1; ++kt) pv(kt);
  for (int kt = 12; kt < 12 + n2; ++kt) pv(kt);
  #pragma unroll
  for (int m = 0; m < 2; ++m)
    #pragma unroll
    for (int n = 0; n < 6; ++n)
      #pragma unroll
      for (int r = 0; r < 4; ++r) {
        int row = m*16 + lg*4 + r;
        int col = v0w + n*16 + li;
        Qp[(size_t)(q0 + row)*384 + col] = (h16)(oacc[m][n][r] * rowscale[row]);
      }
}

// ---------------- attention stage 2 + mean (branch-free skips)
__global__ __launch_bounds__(256) void k_attn2(
    const float* __restrict__ query, const h16* __restrict__ keys,
    const h16* __restrict__ valsT, const int* __restrict__ qlen,
    const int* __restrict__ tlen, const int* __restrict__ ilen,
    float* __restrict__ out)
{
  __shared__ __align__(16) float S[32*516];
  __shared__ __align__(16) h16 UB[32*776];
  __shared__ float rowscale[32];
  int b = blockIdx.x;
  const float* Qp = query + (size_t)b*24*768;
  const h16* Kp = keys + (size_t)b*512*768;
  const h16* Vp = valsT + (size_t)b*768*512;
  int t = threadIdx.x, lane = t & 63, w = t >> 6;
  int lg = lane >> 4, li = lane & 15;
  int ql = qlen[b];
  int TL = tlen[b], IL = ilen[b];
  for (int c = t; c < 3072; c += 256) {
    int row = c / 96, vv = (c % 96) * 8;
    h16x8 a = {};
    if (row < 24 && row < ql) {
      f32x4 f0 = *(const f32x4*)&Qp[(size_t)row*768 + vv];
      f32x4 f1 = *(const f32x4*)&Qp[(size_t)row*768 + vv + 4];
      a[0]=(h16)f0[0]; a[1]=(h16)f0[1]; a[2]=(h16)f0[2]; a[3]=(h16)f0[3];
      a[4]=(h16)f1[0]; a[5]=(h16)f1[1]; a[6]=(h16)f1[2]; a[7]=(h16)f1[3];
    }
    *(h16x8*)&UB[row*776 + vv] = a;
  }
  __syncthreads();
  int kbase = w * 128;
  int LIMw = (w < 3) ? TL : (384 + IL);
  int nvf = (LIMw - kbase + 15) >> 4;
  nvf = nvf < 0 ? 0 : (nvf > 8 ? 8 : nvf);
  for (int nf = 0; nf < nvf; ++nf) {
    int kcol = kbase + nf*16;
    f32x4 acc0 = {0,0,0,0}, acc1 = {0,0,0,0};
    #pragma unroll
    for (int ks = 0; ks < 24; ++ks) {
      h16x8 a0 = *(const h16x8*)&UB[(li)*776      + ks*32 + lg*8];
      h16x8 a1 = *(const h16x8*)&UB[(16 + li)*776 + ks*32 + lg*8];
      h16x8 bk = *(const h16x8*)&Kp[(size_t)(kcol + li)*768 + ks*32 + lg*8];
      acc0 = MFMA(a0, bk, acc0);
      acc1 = MFMA(a1, bk, acc1);
    }
    #pragma unroll
    for (int r = 0; r < 4; ++r) {
      int c = kcol + li;
      float v0 = acc0[r];
      if (v0 == 0.0f) v0 = -__builtin_inff();
      S[(lg*4 + r)*516 + c] = v0;
      float v1 = acc1[r];
      if (v1 == 0.0f) v1 = -__builtin_inff();
      S[(16 + lg*4 + r)*516 + c] = v1;
    }
  }
  for (int nf = nvf; nf < 8; ++nf) {
    int c = kbase + nf*16 + li;
    #pragma unroll
    for (int r = 0; r < 4; ++r) {
      S[(lg*4 + r)*516 + c] = -__builtin_inff();
      S[(16 + lg*4 + r)*516 + c] = -__builtin_inff();
    }
  }
  __syncthreads();
  {
    int row = t >> 3, ci = t & 7;
    float mx = -3e38f;
    for (int j = 0; j < 64; ++j) mx = fmaxf(mx, S[row*516 + ci + j*8]);
    mx = fmaxf(mx, __shfl_xor(mx, 1));
    mx = fmaxf(mx, __shfl_xor(mx, 2));
    mx = fmaxf(mx, __shfl_xor(mx, 4));
    float sum = 0.0f;
    for (int j = 0; j < 64; ++j) {
      float e = __expf(S[row*516 + ci + j*8] - mx);
      S[row*516 + ci + j*8] = e;
      sum += e;
    }
    sum += __shfl_xor(sum, 1);
    sum += __shfl_xor(sum, 2);
    sum += __shfl_xor(sum, 4);
    if (ci == 0) rowscale[row] = 1.0f / (sum > 0.0f ? sum : 1.0f);
  }
  __syncthreads();
  int n1 = (TL + 31) >> 5; n1 = n1 > 12 ? 12 : n1;
  int n2 = (IL + 31) >> 5; n2 = n2 > 4 ? 4 : n2;
  for (int vh = 0; vh < 2; ++vh) {
    f32x4 oacc[2][6] = {};
    auto pv = [&](int kt) {
      int k0 = kt * 32;
      h16x8 bv[6];
      #pragma unroll
      for (int n = 0; n < 6; ++n)
        bv[n] = *(const h16x8*)&Vp[(size_t)(vh*384 + w*96 + n*16 + li)*512 + k0 + lg*8];
      #pragma unroll
      for (int m = 0; m < 2; ++m) {
        int row = m*16 + li;
        f32x4 p0 = *(const f32x4*)&S[row*516 + k0 + lg*8];
        f32x4 p1 = *(const f32x4*)&S[row*516 + k0 + lg*8 + 4];
        h16x8 pa;
        pa[0]=(h16)p0[0]; pa[1]=(h16)p0[1]; pa[2]=(h16)p0[2]; pa[3]=(h16)p0[3];
        pa[4]=(h16)p1[0]; pa[5]=(h16)p1[1]; pa[6]=(h16)p1[2]; pa[7]=(h16)p1[3];
        #pragma unroll
        for (int n = 0; n < 6; ++n)
          oacc[m][n] = MFMA(pa, bv[n], oacc[m][n]);
      }
    };
    for (int kt = 0; kt < n1; ++kt) pv(kt);
    for (int kt = 12; kt < 12 + n2; ++kt) pv(kt);
    #pragma unroll
    for (int n = 0; n < 6; ++n) {
      float cs = 0.0f;
      #pragma unroll
      for (int m = 0; m < 2; ++m)
        #pragma unroll
        for (int r = 0; r < 4; ++r)
          cs += oacc[m][n][r] * rowscale[m*16 + lg*4 + r];
      cs += __shfl_xor(cs, 16);
      cs += __shfl_xor(cs, 32);
      if (lg == 0) out[(size_t)b*768 + vh*384 + w*96 + n*16 + li] = cs * (1.0f/24.0f);
    }
  }
}

extern "C" void kernel_launch(void* const* d_in, const int* in_sizes, int n_in,
                              void* d_out, int out_size, void* d_ws, size_t ws_size,
                              hipStream_t stream)
{
  (void)in_sizes; (void)n_in;
  const float* text  = (const float*)d_in[0];
  const float* images= (const float*)d_in[1];
  const float* query = (const float*)d_in[2];
  const float* ln_g  = (const float*)d_in[3];
  const float* ln_b  = (const float*)d_in[4];
  const float* Wsq = (const float*)d_in[5];
  const float* bsq = (const float*)d_in[6];
  const float* Wiq = (const float*)d_in[7];
  const float* biq = (const float*)d_in[8];
  const float* Wsk = (const float*)d_in[9];
  const float* bsk = (const float*)d_in[10];
  const float* Wik = (const float*)d_in[11];
  const float* bik = (const float*)d_in[12];
  const float* Wsv = (const float*)d_in[13];
  const float* bsv = (const float*)d_in[14];
  const float* Wiv = (const float*)d_in[15];
  const float* biv = (const float*)d_in[16];
  const float* Wkp = (const float*)d_in[17];
  const float* bkp = (const float*)d_in[18];
  const float* Wvp = (const float*)d_in[19];
  const float* bvp = (const float*)d_in[20];
  const int* tlen = (const int*)d_in[21];
  const int* ilen = (const int*)d_in[22];
  const int* qlen = (const int*)d_in[23];

  // ws: [0,256KB) stats; [256KB,+9.4MB) weights; 3x50.33MB Qb/Kb/Vb; [+48MB XN if room]
  const size_t NEED1 = 160694272;
  const size_t NEED2 = NEED1 + 50331648;
  if (ws_size < NEED1) {
    k_diag<<<dim3((out_size+255)/256), dim3(256), 0, stream>>>((float*)d_out, out_size, 1.0e6f);
    return;
  }
  float* muv = (float*)d_ws;
  float* rsd = muv + 32768;
  h16* wb = (h16*)((char*)d_ws + 262144);
  const size_t WSZ = 589824;
  const size_t TSZ = (size_t)32768*768;
  h16* Qb = wb + 8*WSZ;
  h16* Kb = Qb + TSZ;
  h16* Vb = Kb + TSZ;
  h16* XNb = (h16*)((char*)d_ws + NEED1);

  dim3 blk(256);
  k_wprep_all<<<dim3(24,24,14), blk, 0, stream>>>(Wsq, Wiq, Wsk, Wik, Wsv, Wiv, Wkp, Wvp, wb);

  if (ws_size >= NEED2) {
    k_ln<<<dim3(32768), blk, 0, stream>>>(text, images, ln_g, ln_b, XNb);
    k_gemmf2<0><<<dim3(4608), blk, 0, stream>>>(XNb, wb,
        bsq, biq, bsk, bik, bsv, biv, bkp, bvp, Qb, Kb, Vb, tlen, ilen);
  } else {
    k_lnstat<<<dim3(32768), blk, 0, stream>>>(text, images, muv, rsd);
    k_gemmf_fb<<<dim3(4608), blk, 0, stream>>>(text, images, muv, rsd,
        ln_g, ln_b, wb, bsq, biq, bsk, bik, bsv, biv, Qb, Kb, Vb, tlen, ilen);
  }

  k_attn1<<<dim3(16,128), blk, 0, stream>>>(Qb, Kb, Vb, tlen, ilen);

  k_gemmf2<2><<<dim3(3072), blk, 0, stream>>>(Qb, wb,
      bsq, biq, bsk, bik, bsv, biv, bkp, bvp, Kb, Vb, nullptr, tlen, ilen);

  k_attn2<<<dim3(64), blk, 0, stream>>>(query, Kb, Vb, qlen, tlen, ilen, (float*)d_out);
}